// Round 4
// baseline (987.586 us; speedup 1.0000x reference)
//
#include <hip/hip_runtime.h>
#include <math.h>

// Problem constants
#define NN 20000
#define NE 320000
#define FD 128
#define RBFN 20
#define RC_ 5.0f
#define NITER 3
#define NMOL 64
#define F3 384
#define F2 256
#define PI_ 3.14159265358979323846f
#define KB 128
#define LPAD 8
#define SDS 392   // u16 stride per sdrep edge row (384 + 8 pad)

typedef __attribute__((ext_vector_type(8))) short  bf16x8;
typedef __attribute__((ext_vector_type(4))) float  floatx4;
typedef unsigned short u16;
typedef unsigned int   u32;

__device__ __forceinline__ u16 f2b(float x) {
    union { float f; unsigned int u; } v; v.f = x;
    unsigned int u = v.u;
    return (u16)((u + 0x7fffu + ((u >> 16) & 1u)) >> 16);   // RNE
}
__device__ __forceinline__ float b2f(u16 x) {
    union { unsigned int u; float f; } v; v.u = ((unsigned int)x) << 16;
    return v.f;
}
// packed bf16-pair helpers: lo = element 0, hi = element 1
__device__ __forceinline__ float blo(u32 w) {
    union { unsigned int u; float f; } v; v.u = w << 16; return v.f;
}
__device__ __forceinline__ float bhi(u32 w) {
    union { unsigned int u; float f; } v; v.u = w & 0xffff0000u; return v.f;
}
__device__ __forceinline__ u32 pack2(float a, float b) {
    return (u32)f2b(a) | ((u32)f2b(b) << 16);
}

// ---------------------------------------------------------------- weight cvt (once per launch)
__global__ __launch_bounds__(256) void cvt_w_kernel(
    const float* s0, int n0, const float* s1, int n1, const float* s2, int n2,
    const float* s3, int n3, const float* s4, int n4, const float* s5, int n5,
    const float* s6, int n6, u16* __restrict__ dst)
{
    int idx = blockIdx.x * 256 + threadIdx.x;
    if (idx < n0) { dst[idx] = f2b(s0[idx]); return; } idx -= n0; dst += n0;
    if (idx < n1) { dst[idx] = f2b(s1[idx]); return; } idx -= n1; dst += n1;
    if (idx < n2) { dst[idx] = f2b(s2[idx]); return; } idx -= n2; dst += n2;
    if (idx < n3) { dst[idx] = f2b(s3[idx]); return; } idx -= n3; dst += n3;
    if (idx < n4) { dst[idx] = f2b(s4[idx]); return; } idx -= n4; dst += n4;
    if (idx < n5) { dst[idx] = f2b(s5[idx]); return; } idx -= n5; dst += n5;
    if (idx < n6) { dst[idx] = f2b(s6[idx]); }
}

// ew (ITERS,384,20) fp32 -> ewb (ITERS,384,32) bf16, k>=20 zero-padded (MFMA B rows)
__global__ __launch_bounds__(256) void cvt_ew_kernel(const float* __restrict__ ew,
    u16* __restrict__ ewb)
{
    int idx = blockIdx.x * 256 + threadIdx.x;
    if (idx >= NITER * F3 * 32) return;
    int k = idx & 31;
    int row = idx >> 5;
    ewb[idx] = (k < RBFN) ? f2b(ew[row * RBFN + k]) : (u16)0;
}

// ---------------------------------------------------------------- fused init: embed + v zeroing
__global__ __launch_bounds__(256) void init_kernel(const int* __restrict__ z,
    const float* __restrict__ emb, float* __restrict__ s, u16* __restrict__ sbf,
    float* __restrict__ v_a, int* __restrict__ v_pk_i)
{
    int idx = blockIdx.x * 256 + threadIdx.x;
    if (idx < NN * F3) v_a[idx] = 0.f;
    if (idx < NN * F3 / 2) v_pk_i[idx] = 0;
    if (idx < NN * FD) {
        int n = idx >> 7, f = idx & 127;
        float v = emb[z[n] * FD + f];
        s[idx] = v; sbf[idx] = f2b(v);
    }
}

__global__ __launch_bounds__(256) void zero_i_kernel(int* __restrict__ p, int n)
{
    int idx = blockIdx.x * 256 + threadIdx.x;
    if (idx < n) p[idx] = 0;
}

// ---------------------------------------------------------------- CSR build
__global__ __launch_bounds__(256) void csr_count_kernel(const int* __restrict__ graph,
    int* __restrict__ cnt)
{
    int e = blockIdx.x * 256 + threadIdx.x;
    if (e >= NE) return;
    atomicAdd(&cnt[graph[2 * e]], 1);
}

__global__ __launch_bounds__(1024) void csr_scan_kernel(const int* __restrict__ cnt,
    int* __restrict__ row_ptr, int* __restrict__ cursor)
{
    __shared__ int sd[1024];
    int tid = threadIdx.x;
    const int chunk = (NN + 1023) / 1024;
    int start = tid * chunk;
    int end = start + chunk; if (end > NN) end = NN;
    int sum = 0;
    for (int j = start; j < end; j++) sum += cnt[j];
    sd[tid] = sum;
    __syncthreads();
    for (int off = 1; off < 1024; off <<= 1) {
        int v = 0;
        if (tid >= off) v = sd[tid - off];
        __syncthreads();
        if (tid >= off) sd[tid] += v;
        __syncthreads();
    }
    int run = (tid == 0) ? 0 : sd[tid - 1];
    for (int j = start; j < end; j++) {
        row_ptr[j] = run;
        cursor[j]  = run;
        run += cnt[j];
    }
    if (tid == 0) row_ptr[NN] = NE;
}

__global__ __launch_bounds__(256) void csr_scatter_kernel(const int* __restrict__ graph,
    int* __restrict__ cursor, int* __restrict__ edge_list)
{
    int e = blockIdx.x * 256 + threadIdx.x;
    if (e >= NE) return;
    int p = atomicAdd(&cursor[graph[2 * e]], 1);
    edge_list[p] = e;
}

// Permuted edge streams in CSR order: rbf as bf16 MFMA-A rows (K=32 padded), cut/sense/dst.
// sin(k*base) via Chebyshev recurrence: s_{k+1} = 2cos(base)*s_k - s_{k-1} (1 sincos total).
__global__ __launch_bounds__(256) void edge_stream_kernel(
    const int* __restrict__ edge_list, const int* __restrict__ graph,
    const float* __restrict__ dist, const float* __restrict__ sense,
    u16* __restrict__ rbf_bf, float* __restrict__ cut_p,
    float* __restrict__ sense_p, int* __restrict__ dst_p)
{
    int j = blockIdx.x * 256 + threadIdx.x;
    if (j >= NE) return;
    int e = edge_list[j];
    float d = dist[e];
    float inv = 1.f / d;
    float base = PI_ * d / RC_;
    float s1, c1;
    __sincosf(base, &s1, &c1);
    float twoc = c1 + c1;
    u16* rb = rbf_bf + (size_t)j * 32;
    float sprev = 0.f, scur = s1;
    #pragma unroll
    for (int k = 0; k < RBFN; k++) {
        rb[k] = f2b(scur * inv);
        float snext = twoc * scur - sprev;
        sprev = scur; scur = snext;
    }
    #pragma unroll
    for (int k = RBFN; k < 32; k++) rb[k] = 0;
    cut_p[j] = 0.5f * (c1 + 1.f) * (d < RC_ ? 1.f : 0.f);
    dst_p[j] = graph[2 * e + 1];
    sense_p[3 * j + 0] = sense[3 * e + 0];
    sense_p[3 * j + 1] = sense[3 * e + 1];
    sense_p[3 * j + 2] = sense[3 * e + 2];
}

// ---------------------------------------------------------------- fused node MLP
// Ob = (silu(A@W1^T + b1)) @ W2^T + b2.  A:(M,K1) bf16, W1:(128,K1), W2:(384,128).
// PACK layout (for edge gather): row of 384 u16 per node:
//   [0..255]  = (comp0, comp1) interleaved at f*2 + c   (c = gn>>7 for gn<256)
//   [256..383]= comp2 planar at 256 + (gn&127)
template<int K1, bool PACK>
__global__ __launch_bounds__(256) void mlp_kernel(const u16* __restrict__ A,
    const u16* __restrict__ W1, const float* __restrict__ b1,
    const u16* __restrict__ W2, const float* __restrict__ b2,
    u16* __restrict__ Ob, int M)
{
    __shared__ u16 As[64][KB + LPAD];
    __shared__ u16 Ws[128][KB + LPAD];
    __shared__ u16 T[64][KB + LPAD];
    const int bm = blockIdx.x * 64;
    const int tid = threadIdx.x;
    const int wave = tid >> 6, lane = tid & 63;
    const int wm  = (wave >> 1) * 32;
    const int wn1 = (wave & 1) * 64;
    const int wn  = (wave & 1) * 32;
    const int quad = lane >> 4, lr = lane & 15;
    const int r = tid >> 2, q = tid & 3;

    floatx4 acc1[2][4];
    #pragma unroll
    for (int i = 0; i < 2; i++)
        #pragma unroll
        for (int j = 0; j < 4; j++) acc1[i][j] = (floatx4)0.f;

    for (int ko = 0; ko < K1; ko += KB) {
        {
            int gm = bm + r;
            u16* dA = &As[r][q * 32];
            if (gm < M) {
                const u16* ap = A + (size_t)gm * K1 + ko + q * 32;
                #pragma unroll
                for (int x = 0; x < 32; x += 8)
                    *(bf16x8*)&dA[x] = *(const bf16x8*)(ap + x);
            } else {
                #pragma unroll
                for (int x = 0; x < 32; x += 8)
                    *(bf16x8*)&dA[x] = (bf16x8)0;
            }
            #pragma unroll
            for (int h = 0; h < 2; h++) {
                int wr = r + h * 64;
                const u16* wp = W1 + (size_t)wr * K1 + ko + q * 32;
                u16* dW = &Ws[wr][q * 32];
                #pragma unroll
                for (int x = 0; x < 32; x += 8)
                    *(bf16x8*)&dW[x] = *(const bf16x8*)(wp + x);
            }
        }
        __syncthreads();
        #pragma unroll
        for (int kk = 0; kk < KB; kk += 32) {
            bf16x8 a0 = *(const bf16x8*)&As[wm + lr     ][kk + quad * 8];
            bf16x8 a1 = *(const bf16x8*)&As[wm + 16 + lr][kk + quad * 8];
            #pragma unroll
            for (int j = 0; j < 4; j++) {
                bf16x8 b = *(const bf16x8*)&Ws[wn1 + j * 16 + lr][kk + quad * 8];
                acc1[0][j] = __builtin_amdgcn_mfma_f32_16x16x32_bf16(a0, b, acc1[0][j], 0, 0, 0);
                acc1[1][j] = __builtin_amdgcn_mfma_f32_16x16x32_bf16(a1, b, acc1[1][j], 0, 0, 0);
            }
        }
        __syncthreads();
    }
    #pragma unroll
    for (int i = 0; i < 2; i++) {
        #pragma unroll
        for (int j = 0; j < 4; j++) {
            int col = wn1 + j * 16 + lr;
            float bb = b1[col];
            #pragma unroll
            for (int rr = 0; rr < 4; rr++) {
                int row = wm + i * 16 + quad * 4 + rr;
                float v = acc1[i][j][rr] + bb;
                v = v / (1.f + __expf(-v));
                T[row][col] = f2b(v);
            }
        }
    }
    __syncthreads();

    for (int c0 = 0; c0 < F3; c0 += 64) {
        {
            const u16* wp = W2 + (size_t)(c0 + r) * KB + q * 32;
            u16* dW = &Ws[r][q * 32];
            #pragma unroll
            for (int x = 0; x < 32; x += 8)
                *(bf16x8*)&dW[x] = *(const bf16x8*)(wp + x);
        }
        __syncthreads();
        floatx4 acc2[2][2];
        #pragma unroll
        for (int i = 0; i < 2; i++)
            #pragma unroll
            for (int j = 0; j < 2; j++) acc2[i][j] = (floatx4)0.f;
        #pragma unroll
        for (int kk = 0; kk < KB; kk += 32) {
            bf16x8 a0 = *(const bf16x8*)&T[wm + lr     ][kk + quad * 8];
            bf16x8 a1 = *(const bf16x8*)&T[wm + 16 + lr][kk + quad * 8];
            bf16x8 b0 = *(const bf16x8*)&Ws[wn + lr     ][kk + quad * 8];
            bf16x8 b1 = *(const bf16x8*)&Ws[wn + 16 + lr][kk + quad * 8];
            acc2[0][0] = __builtin_amdgcn_mfma_f32_16x16x32_bf16(a0, b0, acc2[0][0], 0, 0, 0);
            acc2[0][1] = __builtin_amdgcn_mfma_f32_16x16x32_bf16(a0, b1, acc2[0][1], 0, 0, 0);
            acc2[1][0] = __builtin_amdgcn_mfma_f32_16x16x32_bf16(a1, b0, acc2[1][0], 0, 0, 0);
            acc2[1][1] = __builtin_amdgcn_mfma_f32_16x16x32_bf16(a1, b1, acc2[1][1], 0, 0, 0);
        }
        #pragma unroll
        for (int i = 0; i < 2; i++) {
            #pragma unroll
            for (int j = 0; j < 2; j++) {
                int gn = c0 + wn + j * 16 + lr;
                float bb = b2[gn];
                #pragma unroll
                for (int rr = 0; rr < 4; rr++) {
                    int gm = bm + wm + i * 16 + quad * 4 + rr;
                    if (gm < M) {
                        u16 val = f2b(acc2[i][j][rr] + bb);
                        if (PACK) {
                            int off = (gn < 256) ? ((gn & 127) * 2 + (gn >> 7))
                                                 : (256 + (gn & 127));
                            Ob[(size_t)gm * F3 + off] = val;
                        } else {
                            Ob[(size_t)gm * F3 + gn] = val;
                        }
                    }
                }
            }
        }
        __syncthreads();
    }
}

// Dual GEMM: U = A@Wu^T, V = A@Wv^T (K=128, Nc=128). bf16 outs.
__global__ __launch_bounds__(256) void gemm_uv(const u16* __restrict__ A,
    const u16* __restrict__ Wu, const u16* __restrict__ Wv,
    u16* __restrict__ U, u16* __restrict__ V, int M)
{
    __shared__ u16 As[64][KB + LPAD];
    __shared__ u16 Bu[64][KB + LPAD];
    __shared__ u16 Bv[64][KB + LPAD];
    const int bm = blockIdx.x * 64;
    const int bn = blockIdx.y * 64;
    const int tid = threadIdx.x;
    const int r = tid >> 2;
    const int q = tid & 3;
    const int wave = tid >> 6;
    const int lane = tid & 63;
    const int wm = (wave >> 1) * 32;
    const int wn = (wave & 1) * 32;
    const int quad = lane >> 4;
    const int lr = lane & 15;

    floatx4 au[2][2], av[2][2];
    #pragma unroll
    for (int i = 0; i < 2; i++)
        #pragma unroll
        for (int j = 0; j < 2; j++) { au[i][j] = (floatx4)0.f; av[i][j] = (floatx4)0.f; }

    {
        int gm = bm + r;
        u16* dA = &As[r][q * 32];
        if (gm < M) {
            const u16* ap = A + (size_t)gm * KB + q * 32;
            #pragma unroll
            for (int x = 0; x < 32; x += 8)
                *(bf16x8*)&dA[x] = *(const bf16x8*)(ap + x);
        } else {
            #pragma unroll
            for (int x = 0; x < 32; x += 8)
                *(bf16x8*)&dA[x] = (bf16x8)0;
        }
        int gn = bn + r;
        const u16* up = Wu + (size_t)gn * KB + q * 32;
        const u16* vp = Wv + (size_t)gn * KB + q * 32;
        u16* dU = &Bu[r][q * 32];
        u16* dV = &Bv[r][q * 32];
        #pragma unroll
        for (int x = 0; x < 32; x += 8) {
            *(bf16x8*)&dU[x] = *(const bf16x8*)(up + x);
            *(bf16x8*)&dV[x] = *(const bf16x8*)(vp + x);
        }
    }
    __syncthreads();
    #pragma unroll
    for (int kk = 0; kk < KB; kk += 32) {
        bf16x8 a0 = *(const bf16x8*)&As[wm + lr     ][kk + quad * 8];
        bf16x8 a1 = *(const bf16x8*)&As[wm + 16 + lr][kk + quad * 8];
        bf16x8 u0 = *(const bf16x8*)&Bu[wn + lr     ][kk + quad * 8];
        bf16x8 u1 = *(const bf16x8*)&Bu[wn + 16 + lr][kk + quad * 8];
        bf16x8 v0 = *(const bf16x8*)&Bv[wn + lr     ][kk + quad * 8];
        bf16x8 v1 = *(const bf16x8*)&Bv[wn + 16 + lr][kk + quad * 8];
        au[0][0] = __builtin_amdgcn_mfma_f32_16x16x32_bf16(a0, u0, au[0][0], 0, 0, 0);
        au[0][1] = __builtin_amdgcn_mfma_f32_16x16x32_bf16(a0, u1, au[0][1], 0, 0, 0);
        au[1][0] = __builtin_amdgcn_mfma_f32_16x16x32_bf16(a1, u0, au[1][0], 0, 0, 0);
        au[1][1] = __builtin_amdgcn_mfma_f32_16x16x32_bf16(a1, u1, au[1][1], 0, 0, 0);
        av[0][0] = __builtin_amdgcn_mfma_f32_16x16x32_bf16(a0, v0, av[0][0], 0, 0, 0);
        av[0][1] = __builtin_amdgcn_mfma_f32_16x16x32_bf16(a0, v1, av[0][1], 0, 0, 0);
        av[1][0] = __builtin_amdgcn_mfma_f32_16x16x32_bf16(a1, v0, av[1][0], 0, 0, 0);
        av[1][1] = __builtin_amdgcn_mfma_f32_16x16x32_bf16(a1, v1, av[1][1], 0, 0, 0);
    }
    #pragma unroll
    for (int i = 0; i < 2; i++) {
        #pragma unroll
        for (int j = 0; j < 2; j++) {
            int gn = bn + wn + j * 16 + lr;
            #pragma unroll
            for (int rr = 0; rr < 4; rr++) {
                int gm = bm + wm + i * 16 + quad * 4 + rr;
                if (gm < M) {
                    U[(size_t)gm * FD + gn] = f2b(au[i][j][rr]);
                    V[(size_t)gm * FD + gn] = f2b(av[i][j][rr]);
                }
            }
        }
    }
}

// ---------------------------------------------------------------- edge aggregate (MFMA dist_rep)
// 512 threads/node (8 waves). Per 16-edge tile: dist_rep via 24 MFMAs (3 col-tiles/wave)
// -> planar bf16 sdrep in LDS; aggregation: 4 groups of 128 threads, each handling up to
// 4 edges serially (per-thread loop body byte-identical to the proven 256-thread form).
__global__ __launch_bounds__(512) void edge_mfma_kernel(
    const u16* __restrict__ rbf_bf, const float* __restrict__ cut_p,
    const float* __restrict__ sense_p, const int* __restrict__ dst_p,
    const u16* __restrict__ ewb, const float* __restrict__ eb,
    const u16* __restrict__ a_pk, const float* __restrict__ s_in,
    const float* __restrict__ v_in, const u16* __restrict__ v_pk,
    const int* __restrict__ row_ptr,
    float* __restrict__ s_out, u16* __restrict__ s_obf,
    float* __restrict__ v_out, u16* __restrict__ v_obf)
{
    __shared__ __align__(16) u16 sdrep[16 * SDS];   // planar bf16: [e][col] — 12.25 KB; aliased as red[] at end
    __shared__ float scut[16];
    __shared__ float ssen[16][4];
    __shared__ int   sdst[16];

    const int n = blockIdx.x;
    const int tid = threadIdx.x;
    const int wave = tid >> 6;          // 0..7
    const int lane = tid & 63;
    const int quad = lane >> 4;
    const int lr = lane & 15;
    const int f = tid & 127;
    const int grp = tid >> 7;           // 0..3

    int beg = row_ptr[n], end = row_ptr[n + 1];
    float accs = 0.f, accv0 = 0.f, accv1 = 0.f, accv2 = 0.f;

    for (int t0 = beg; t0 < end; t0 += 16) {
        int cnt = end - t0; if (cnt > 16) cnt = 16;
        __syncthreads();   // previous tile fully consumed
        if (tid < 16) {
            scut[tid] = (tid < cnt) ? cut_p[t0 + tid] : 0.f;
            sdst[tid] = (tid < cnt) ? dst_p[t0 + tid] : 0;
        }
        if (tid >= 64 && tid < 64 + 3 * cnt) {
            int x = tid - 64;
            ssen[x / 3][x % 3] = sense_p[3 * t0 + x];
        }
        // MFMA: A = rbf rows (lane m=lr = edge), B = ew rows (3 col-tiles/wave x 8 waves)
        bf16x8 afrag;
        int ge = t0 + lr;
        if (ge < end) afrag = *(const bf16x8*)&rbf_bf[(size_t)ge * 32 + quad * 8];
        else          afrag = (bf16x8)0;
        floatx4 dacc[3];
        #pragma unroll
        for (int nt = 0; nt < 3; nt++) {
            int nrow = (wave * 3 + nt) * 16 + lr;
            bf16x8 bfrag = *(const bf16x8*)&ewb[(size_t)nrow * 32 + quad * 8];
            dacc[nt] = __builtin_amdgcn_mfma_f32_16x16x32_bf16(afrag, bfrag, (floatx4)0.f, 0, 0, 0);
        }
        __syncthreads();   // staged scalars visible
        // epilogue: (d + eb) * cut -> planar bf16 sdrep; C/D layout col=lr, row(edge)=quad*4+rr
        #pragma unroll
        for (int nt = 0; nt < 3; nt++) {
            int ncol = (wave * 3 + nt) * 16 + lr;
            float ebn = eb[ncol];
            #pragma unroll
            for (int rr = 0; rr < 4; rr++) {
                int e = quad * 4 + rr;
                sdrep[e * SDS + ncol] = f2b((dacc[nt][rr] + ebn) * scut[e]);
            }
        }
        __syncthreads();   // sdrep ready
        // aggregation: group g handles up to 4 edges (serial runtime-bound loop — proven form)
        int nh = cnt - grp * 4; if (nh > 4) nh = 4; if (nh < 0) nh = 0;
        for (int k = 0; k < nh; k++) {
            int e = grp * 4 + k;
            int dst = sdst[e];
            const u16* sr = &sdrep[e * SDS];
            float drv = b2f(sr[f]);
            float drs = b2f(sr[FD + f]);
            float drd = b2f(sr[2 * FD + f]);
            const u16* ar = a_pk + (size_t)dst * F3;
            u32 ap = *(const u32*)(ar + f * 2);
            float rv = b2f((u16)(ap & 0xffff)) * drv;
            float rs = b2f((u16)(ap >> 16))    * drs;
            float rd = b2f(ar[256 + f])        * drd;
            accs += rs;
            const u16* vr = v_pk + (size_t)dst * F3;
            u32 vp = *(const u32*)(vr + f * 2);
            accv0 += b2f((u16)(vp & 0xffff)) * rv + ssen[e][0] * rd;
            accv1 += b2f((u16)(vp >> 16))    * rv + ssen[e][1] * rd;
            accv2 += b2f(vr[256 + f])        * rv + ssen[e][2] * rd;
        }
    }
    // combine 4 groups through LDS (aliased onto sdrep), group 0 writes
    __syncthreads();
    float* red = (float*)sdrep;   // 3 groups x 4 streams x 128 floats = 6 KB <= 12.25 KB
    if (grp > 0) {
        float* rb = red + (grp - 1) * 512;
        rb[f] = accs; rb[128 + f] = accv0; rb[256 + f] = accv1; rb[384 + f] = accv2;
    }
    __syncthreads();
    if (grp == 0) {
        accs  += red[f]       + red[512 + f]       + red[1024 + f];
        accv0 += red[128 + f] + red[512 + 128 + f] + red[1024 + 128 + f];
        accv1 += red[256 + f] + red[512 + 256 + f] + red[1024 + 256 + f];
        accv2 += red[384 + f] + red[512 + 384 + f] + red[1024 + 384 + f];
        int nb = n * FD + f;
        float so = s_in[nb] + 2.f * accs;
        s_out[nb] = so; s_obf[nb] = f2b(so);
        int vb = n * F3 + f;
        float w0 = v_in[vb]           + 2.f * accv0;
        float w1 = v_in[vb + FD]      + 2.f * accv1;
        float w2 = v_in[vb + 2 * FD]  + 2.f * accv2;
        v_out[vb]          = w0; v_obf[vb]          = f2b(w0);
        v_out[vb + FD]     = w1; v_obf[vb + FD]     = f2b(w1);
        v_out[vb + 2 * FD] = w2; v_obf[vb + 2 * FD] = f2b(w2);
    }
}

// ---------------------------------------------------------------- h build (bf16): [s, |Vv|]
__global__ __launch_bounds__(256) void build_h_kernel(const u16* __restrict__ sbf,
    const u16* __restrict__ Vv, u16* __restrict__ h)
{
    int idx = blockIdx.x * 256 + threadIdx.x;
    if (idx >= NN * 64) return;
    int n = idx >> 6, l = idx & 63;
    u32 sp = *(const u32*)&sbf[n * FD + 2 * l];
    int vb = n * F3 + 2 * l;
    u32 x0 = *(const u32*)&Vv[vb];
    u32 x1 = *(const u32*)&Vv[vb + FD];
    u32 x2 = *(const u32*)&Vv[vb + 2 * FD];
    *(u32*)&h[n * F2 + 2 * l] = sp;
    float a0 = blo(x0), a1 = blo(x1), a2 = blo(x2);
    float b0 = bhi(x0), b1 = bhi(x1), b2 = bhi(x2);
    float n0 = sqrtf(a0 * a0 + a1 * a1 + a2 * a2);
    float n1 = sqrtf(b0 * b0 + b1 * b1 + b2 * b2);
    *(u32*)&h[n * F2 + FD + 2 * l] = pack2(n0, n1);
}

// ---------------------------------------------------------------- node update (f-pair vectorized)
__global__ __launch_bounds__(256) void update_kernel(const float* __restrict__ s_mid,
    const float* __restrict__ v_mid, const u16* __restrict__ a2,
    const u16* __restrict__ Uv, const u16* __restrict__ Vv,
    float* __restrict__ s_out, u16* __restrict__ s_obf,
    float* __restrict__ v_out, u16* __restrict__ v_pk)
{
    int idx = blockIdx.x * 256 + threadIdx.x;
    if (idx >= NN * 64) return;
    int n = idx >> 6, l = idx & 63;
    int vb = n * F3 + 2 * l;
    u32 u0p = *(const u32*)&Uv[vb];
    u32 u1p = *(const u32*)&Uv[vb + FD];
    u32 u2p = *(const u32*)&Uv[vb + 2 * FD];
    u32 w0p = *(const u32*)&Vv[vb];
    u32 w1p = *(const u32*)&Vv[vb + FD];
    u32 w2p = *(const u32*)&Vv[vb + 2 * FD];
    u32 avp = *(const u32*)&a2[vb];
    u32 asp = *(const u32*)&a2[vb + FD];
    u32 ssp = *(const u32*)&a2[vb + 2 * FD];
    int nb = n * FD + 2 * l;
    float2 sm  = *(const float2*)&s_mid[nb];
    float2 vm0 = *(const float2*)&v_mid[vb];
    float2 vm1 = *(const float2*)&v_mid[vb + FD];
    float2 vm2 = *(const float2*)&v_mid[vb + 2 * FD];
    // f0 (lo)
    float u0 = blo(u0p), u1 = blo(u1p), u2 = blo(u2p);
    float w0 = blo(w0p), w1 = blo(w1p), w2 = blo(w2p);
    float dot0 = u0 * w0 + u1 * w1 + u2 * w2;
    float avv0 = blo(avp), asv0 = blo(asp), ass0 = blo(ssp);
    float so0 = sm.x + ass0 + asv0 * dot0;
    float y00 = vm0.x + avv0 * u0;
    float y10 = vm1.x + avv0 * u1;
    float y20 = vm2.x + avv0 * u2;
    // f1 (hi)
    float U0 = bhi(u0p), U1 = bhi(u1p), U2 = bhi(u2p);
    float W0 = bhi(w0p), W1 = bhi(w1p), W2 = bhi(w2p);
    float dot1 = U0 * W0 + U1 * W1 + U2 * W2;
    float avv1 = bhi(avp), asv1 = bhi(asp), ass1 = bhi(ssp);
    float so1 = sm.y + ass1 + asv1 * dot1;
    float y01 = vm0.y + avv1 * U0;
    float y11 = vm1.y + avv1 * U1;
    float y21 = vm2.y + avv1 * U2;
    *(float2*)&s_out[nb] = make_float2(so0, so1);
    *(u32*)&s_obf[nb] = pack2(so0, so1);
    *(float2*)&v_out[vb]          = make_float2(y00, y01);
    *(float2*)&v_out[vb + FD]     = make_float2(y10, y11);
    *(float2*)&v_out[vb + 2 * FD] = make_float2(y20, y21);
    char* vpb = (char*)v_pk + (u32)n * (2 * F3);
    uint2 pr;
    pr.x = pack2(y00, y10);     // f0: (c0,c1)
    pr.y = pack2(y01, y11);     // f1: (c0,c1)
    *(uint2*)(vpb + 8 * l) = pr;
    *(u32*)(vpb + 512 + 4 * l) = pack2(y20, y21);   // planar c2 for f0,f1
}

// ---------------------------------------------------------------- fused final head
// t = silu(s@ow1^T + ob1); nodeval[n] = t[n,:]·ow2 + ob2.  One block = 64 nodes, full K=Nc=128.
__global__ __launch_bounds__(256) void head_kernel(const u16* __restrict__ A,
    const u16* __restrict__ W1, const float* __restrict__ b1,
    const float* __restrict__ ow2, const float* __restrict__ ob2,
    float* __restrict__ nodeval)
{
    __shared__ u16 As[64][KB + LPAD];
    __shared__ u16 Ws[128][KB + LPAD];
    __shared__ float T[64][KB + 4];
    __shared__ float ow2s[KB];
    const int bm = blockIdx.x * 64;
    const int tid = threadIdx.x;
    const int wave = tid >> 6, lane = tid & 63;
    const int wm  = (wave >> 1) * 32;
    const int wn1 = (wave & 1) * 64;
    const int quad = lane >> 4, lr = lane & 15;
    const int r = tid >> 2, q = tid & 3;

    if (tid < KB) ow2s[tid] = ow2[tid];

    floatx4 acc1[2][4];
    #pragma unroll
    for (int i = 0; i < 2; i++)
        #pragma unroll
        for (int j = 0; j < 4; j++) acc1[i][j] = (floatx4)0.f;

    {
        int gm = bm + r;
        u16* dA = &As[r][q * 32];
        if (gm < NN) {
            const u16* ap = A + (size_t)gm * KB + q * 32;
            #pragma unroll
            for (int x = 0; x < 32; x += 8)
                *(bf16x8*)&dA[x] = *(const bf16x8*)(ap + x);
        } else {
            #pragma unroll
            for (int x = 0; x < 32; x += 8)
                *(bf16x8*)&dA[x] = (bf16x8)0;
        }
        #pragma unroll
        for (int h = 0; h < 2; h++) {
            int wr = r + h * 64;
            const u16* wp = W1 + (size_t)wr * KB + q * 32;
            u16* dW = &Ws[wr][q * 32];
            #pragma unroll
            for (int x = 0; x < 32; x += 8)
                *(bf16x8*)&dW[x] = *(const bf16x8*)(wp + x);
        }
    }
    __syncthreads();
    #pragma unroll
    for (int kk = 0; kk < KB; kk += 32) {
        bf16x8 a0 = *(const bf16x8*)&As[wm + lr     ][kk + quad * 8];
        bf16x8 a1 = *(const bf16x8*)&As[wm + 16 + lr][kk + quad * 8];
        #pragma unroll
        for (int j = 0; j < 4; j++) {
            bf16x8 b = *(const bf16x8*)&Ws[wn1 + j * 16 + lr][kk + quad * 8];
            acc1[0][j] = __builtin_amdgcn_mfma_f32_16x16x32_bf16(a0, b, acc1[0][j], 0, 0, 0);
            acc1[1][j] = __builtin_amdgcn_mfma_f32_16x16x32_bf16(a1, b, acc1[1][j], 0, 0, 0);
        }
    }
    #pragma unroll
    for (int i = 0; i < 2; i++) {
        #pragma unroll
        for (int j = 0; j < 4; j++) {
            int col = wn1 + j * 16 + lr;
            float bb = b1[col];
            #pragma unroll
            for (int rr = 0; rr < 4; rr++) {
                int row = wm + i * 16 + quad * 4 + rr;
                float v = acc1[i][j][rr] + bb;
                v = v / (1.f + __expf(-v));
                T[row][col] = v;
            }
        }
    }
    __syncthreads();
    // dot with ow2: 4 threads per node, 32 cols each, shfl-reduce
    int nl = tid >> 2, seg = tid & 3;
    float v = 0.f;
    #pragma unroll
    for (int x = 0; x < 32; x++) {
        int col = seg * 32 + x;
        v += T[nl][col] * ow2s[col];
    }
    v += __shfl_down(v, 2);
    v += __shfl_down(v, 1);
    if (seg == 0) {
        int gm = bm + nl;
        if (gm < NN) nodeval[gm] = v + ob2[0];
    }
}

__global__ __launch_bounds__(1024) void mol_reduce_kernel(const float* __restrict__ nodeval,
    const int* __restrict__ gidx, float* __restrict__ out)
{
    __shared__ float mol[NMOL];
    int tid = threadIdx.x;
    if (tid < NMOL) mol[tid] = 0.f;
    __syncthreads();
    int cur = -1; float acc = 0.f;
    for (int x = tid; x < NN; x += 1024) {
        int g = gidx[x];
        float v = nodeval[x];
        if (g != cur) {
            if (cur >= 0) atomicAdd(&mol[cur], acc);
            cur = g; acc = v;
        } else acc += v;
    }
    if (cur >= 0) atomicAdd(&mol[cur], acc);
    __syncthreads();
    if (tid < NMOL) out[tid] = mol[tid];
}

// ---------------------------------------------------------------- launch
extern "C" void kernel_launch(void* const* d_in, const int* in_sizes, int n_in,
                              void* d_out, int out_size, void* d_ws, size_t ws_size,
                              hipStream_t stream)
{
    const int*   z     = (const int*)d_in[0];
    const int*   graph = (const int*)d_in[1];
    const float* dist  = (const float*)d_in[2];
    const float* sense = (const float*)d_in[3];
    const int*   gidx  = (const int*)d_in[4];
    const float* emb   = (const float*)d_in[5];
    const float* mw1   = (const float*)d_in[6];
    const float* mb1   = (const float*)d_in[7];
    const float* mw2   = (const float*)d_in[8];
    const float* mb2   = (const float*)d_in[9];
    const float* ew    = (const float*)d_in[10];
    const float* eb    = (const float*)d_in[11];
    const float* uw    = (const float*)d_in[12];
    const float* vw    = (const float*)d_in[13];
    const float* aw1   = (const float*)d_in[14];
    const float* ab1   = (const float*)d_in[15];
    const float* aw2   = (const float*)d_in[16];
    const float* ab2   = (const float*)d_in[17];
    const float* ow1   = (const float*)d_in[18];
    const float* ob1   = (const float*)d_in[19];
    const float* ow2   = (const float*)d_in[20];
    const float* ob2   = (const float*)d_in[21];
    float* out = (float*)d_out;

    // ---- workspace carve-up ----
    float* W = (float*)d_ws;
    float* s_a    = W; W += (size_t)NN * FD;
    float* s_b    = W; W += (size_t)NN * FD;
    float* v_a    = W; W += (size_t)NN * F3;
    float* v_b    = W; W += (size_t)NN * F3;
    float* cut_p  = W; W += (size_t)NE;
    float* sns_p  = W; W += (size_t)NE * 3;
    float* nodeval= W; W += (size_t)NN;
    u16* U = (u16*)W;
    u16* sbf_a = U; U += (size_t)NN * FD;
    u16* sbf_b = U; U += (size_t)NN * FD;
    u16* vbf_b = U; U += (size_t)NN * F3;
    u16* a_pk  = U; U += (size_t)NN * F3;
    u16* v_pk  = U; U += (size_t)NN * F3;
    u16* h_bf  = U; U += (size_t)NN * F2;
    u16* a2_bf = U; U += (size_t)NN * F3;
    u16* Uv_bf = U; U += (size_t)NN * F3;
    u16* Vv_bf = U; U += (size_t)NN * F3;
    u16* rbf_bf= U; U += (size_t)NE * 32;
    u16* ewb   = U; U += (size_t)NITER * F3 * 32;
    u16* wb    = U; U += 557056;
    int* ip = (int*)U;
    int* row_ptr   = ip; ip += NN + 1;
    int* cnt       = ip; ip += NN;
    int* cursor    = ip; ip += NN;
    int* edge_list = ip; ip += NE;
    int* dst_p     = ip; ip += NE;

    // bf16 weight table offsets
    u16* wb_mw1 = wb;            // 3*128*128
    u16* wb_mw2 = wb + 49152;    // 3*384*128
    u16* wb_uw  = wb + 196608;   // 3*128*128
    u16* wb_vw  = wb + 245760;   // 3*128*128
    u16* wb_aw1 = wb + 294912;   // 3*128*256
    u16* wb_aw2 = wb + 393216;   // 3*384*128
    u16* wb_ow1 = wb + 540672;   // 128*128
    const int WTOT = 557056;

    const int TB = 256;
    dim3 b256(TB);

    // --- precompute ---
    cvt_w_kernel<<<dim3((WTOT + TB - 1) / TB), b256, 0, stream>>>(
        mw1, 49152, mw2, 147456, uw, 49152, vw, 49152, aw1, 98304, aw2, 147456,
        ow1, 16384, wb);
    cvt_ew_kernel<<<dim3((NITER * F3 * 32 + TB - 1) / TB), b256, 0, stream>>>(ew, ewb);
    init_kernel<<<dim3((NN * F3 + TB - 1) / TB), b256, 0, stream>>>(
        z, emb, s_a, sbf_a, v_a, (int*)v_pk);
    zero_i_kernel<<<dim3((NN + TB - 1) / TB), b256, 0, stream>>>(cnt, NN);
    csr_count_kernel<<<dim3((NE + TB - 1) / TB), b256, 0, stream>>>(graph, cnt);
    csr_scan_kernel<<<dim3(1), dim3(1024), 0, stream>>>(cnt, row_ptr, cursor);
    csr_scatter_kernel<<<dim3((NE + TB - 1) / TB), b256, 0, stream>>>(graph, cursor, edge_list);
    edge_stream_kernel<<<dim3((NE + TB - 1) / TB), b256, 0, stream>>>(
        edge_list, graph, dist, sense, rbf_bf, cut_p, sns_p, dst_p);

    dim3 gM((NN + 63) / 64);                   // fused MLPs / head
    dim3 gV2((3 * NN + 63) / 64, FD / 64);     // M=3N, Nc=128
    dim3 gPair((NN * 64 + TB - 1) / TB);       // f-pair elementwise kernels

    for (int i = 0; i < NITER; i++) {
        mlp_kernel<128, true><<<gM, b256, 0, stream>>>(sbf_a,
            wb_mw1 + (size_t)i * FD * FD, mb1 + (size_t)i * FD,
            wb_mw2 + (size_t)i * F3 * FD, mb2 + (size_t)i * F3, a_pk, NN);
        edge_mfma_kernel<<<dim3(NN), dim3(512), 0, stream>>>(
            rbf_bf, cut_p, sns_p, dst_p,
            ewb + (size_t)i * F3 * 32, eb + (size_t)i * F3,
            a_pk, s_a, v_a, v_pk, row_ptr, s_b, sbf_b, v_b, vbf_b);
        gemm_uv<<<gV2, b256, 0, stream>>>(vbf_b, wb_uw + (size_t)i * FD * FD,
            wb_vw + (size_t)i * FD * FD, Uv_bf, Vv_bf, 3 * NN);
        build_h_kernel<<<gPair, b256, 0, stream>>>(sbf_b, Vv_bf, h_bf);
        mlp_kernel<256, false><<<gM, b256, 0, stream>>>(h_bf,
            wb_aw1 + (size_t)i * FD * F2, ab1 + (size_t)i * FD,
            wb_aw2 + (size_t)i * F3 * FD, ab2 + (size_t)i * F3, a2_bf, NN);
        update_kernel<<<gPair, b256, 0, stream>>>(
            s_b, v_b, a2_bf, Uv_bf, Vv_bf, s_a, sbf_a, v_a, v_pk);
    }

    head_kernel<<<gM, b256, 0, stream>>>(sbf_a, wb_ow1, ob1, ow2, ob2, nodeval);
    mol_reduce_kernel<<<dim3(1), dim3(1024), 0, stream>>>(nodeval, gidx, out);
}

// Round 5
// 873.046 us; speedup vs baseline: 1.1312x; 1.1312x over previous
//
#include <hip/hip_runtime.h>
#include <math.h>

// Problem constants
#define NN 20000
#define NE 320000
#define FD 128
#define RBFN 20
#define RC_ 5.0f
#define NITER 3
#define NMOL 64
#define F3 384
#define F2 256
#define PI_ 3.14159265358979323846f
#define KB 128
#define LPAD 8
#define SDS 392   // u16 stride per sdrep edge row (384 + 8 pad)

typedef __attribute__((ext_vector_type(8))) short  bf16x8;
typedef __attribute__((ext_vector_type(4))) float  floatx4;
typedef unsigned short u16;
typedef unsigned int   u32;

__device__ __forceinline__ u16 f2b(float x) {
    union { float f; unsigned int u; } v; v.f = x;
    unsigned int u = v.u;
    return (u16)((u + 0x7fffu + ((u >> 16) & 1u)) >> 16);   // RNE
}
__device__ __forceinline__ float b2f(u16 x) {
    union { unsigned int u; float f; } v; v.u = ((unsigned int)x) << 16;
    return v.f;
}
// packed bf16-pair helpers: lo = element 0, hi = element 1
__device__ __forceinline__ float blo(u32 w) {
    union { unsigned int u; float f; } v; v.u = w << 16; return v.f;
}
__device__ __forceinline__ float bhi(u32 w) {
    union { unsigned int u; float f; } v; v.u = w & 0xffff0000u; return v.f;
}
__device__ __forceinline__ u32 pack2(float a, float b) {
    return (u32)f2b(a) | ((u32)f2b(b) << 16);
}

// ---------------------------------------------------------------- weight cvt (once per launch)
__global__ __launch_bounds__(256) void cvt_w_kernel(
    const float* s0, int n0, const float* s1, int n1, const float* s2, int n2,
    const float* s3, int n3, const float* s4, int n4, const float* s5, int n5,
    const float* s6, int n6, u16* __restrict__ dst)
{
    int idx = blockIdx.x * 256 + threadIdx.x;
    if (idx < n0) { dst[idx] = f2b(s0[idx]); return; } idx -= n0; dst += n0;
    if (idx < n1) { dst[idx] = f2b(s1[idx]); return; } idx -= n1; dst += n1;
    if (idx < n2) { dst[idx] = f2b(s2[idx]); return; } idx -= n2; dst += n2;
    if (idx < n3) { dst[idx] = f2b(s3[idx]); return; } idx -= n3; dst += n3;
    if (idx < n4) { dst[idx] = f2b(s4[idx]); return; } idx -= n4; dst += n4;
    if (idx < n5) { dst[idx] = f2b(s5[idx]); return; } idx -= n5; dst += n5;
    if (idx < n6) { dst[idx] = f2b(s6[idx]); }
}

// ew (ITERS,384,20) fp32 -> ewb (ITERS,384,32) bf16, k>=20 zero-padded (MFMA B rows)
__global__ __launch_bounds__(256) void cvt_ew_kernel(const float* __restrict__ ew,
    u16* __restrict__ ewb)
{
    int idx = blockIdx.x * 256 + threadIdx.x;
    if (idx >= NITER * F3 * 32) return;
    int k = idx & 31;
    int row = idx >> 5;
    ewb[idx] = (k < RBFN) ? f2b(ew[row * RBFN + k]) : (u16)0;
}

// ---------------------------------------------------------------- fused init: embed + v zeroing
__global__ __launch_bounds__(256) void init_kernel(const int* __restrict__ z,
    const float* __restrict__ emb, float* __restrict__ s, u16* __restrict__ sbf,
    float* __restrict__ v_a, int* __restrict__ v_pk_i)
{
    int idx = blockIdx.x * 256 + threadIdx.x;
    if (idx < NN * F3) v_a[idx] = 0.f;
    if (idx < NN * F3 / 2) v_pk_i[idx] = 0;
    if (idx < NN * FD) {
        int n = idx >> 7, f = idx & 127;
        float v = emb[z[n] * FD + f];
        s[idx] = v; sbf[idx] = f2b(v);
    }
}

__global__ __launch_bounds__(256) void zero_i_kernel(int* __restrict__ p, int n)
{
    int idx = blockIdx.x * 256 + threadIdx.x;
    if (idx < n) p[idx] = 0;
}

// ---------------------------------------------------------------- CSR build
__global__ __launch_bounds__(256) void csr_count_kernel(const int* __restrict__ graph,
    int* __restrict__ cnt)
{
    int e = blockIdx.x * 256 + threadIdx.x;
    if (e >= NE) return;
    atomicAdd(&cnt[graph[2 * e]], 1);
}

__global__ __launch_bounds__(1024) void csr_scan_kernel(const int* __restrict__ cnt,
    int* __restrict__ row_ptr, int* __restrict__ cursor)
{
    __shared__ int sd[1024];
    int tid = threadIdx.x;
    const int chunk = (NN + 1023) / 1024;
    int start = tid * chunk;
    int end = start + chunk; if (end > NN) end = NN;
    int sum = 0;
    for (int j = start; j < end; j++) sum += cnt[j];
    sd[tid] = sum;
    __syncthreads();
    for (int off = 1; off < 1024; off <<= 1) {
        int v = 0;
        if (tid >= off) v = sd[tid - off];
        __syncthreads();
        if (tid >= off) sd[tid] += v;
        __syncthreads();
    }
    int run = (tid == 0) ? 0 : sd[tid - 1];
    for (int j = start; j < end; j++) {
        row_ptr[j] = run;
        cursor[j]  = run;
        run += cnt[j];
    }
    if (tid == 0) row_ptr[NN] = NE;
}

__global__ __launch_bounds__(256) void csr_scatter_kernel(const int* __restrict__ graph,
    int* __restrict__ cursor, int* __restrict__ edge_list)
{
    int e = blockIdx.x * 256 + threadIdx.x;
    if (e >= NE) return;
    int p = atomicAdd(&cursor[graph[2 * e]], 1);
    edge_list[p] = e;
}

// Permuted edge streams in CSR order: rbf as bf16 MFMA-A rows (K=32 padded), cut/sense/dst.
// sin(k*base) via Chebyshev recurrence: s_{k+1} = 2cos(base)*s_k - s_{k-1} (1 sincos total).
__global__ __launch_bounds__(256) void edge_stream_kernel(
    const int* __restrict__ edge_list, const int* __restrict__ graph,
    const float* __restrict__ dist, const float* __restrict__ sense,
    u16* __restrict__ rbf_bf, float* __restrict__ cut_p,
    float* __restrict__ sense_p, int* __restrict__ dst_p)
{
    int j = blockIdx.x * 256 + threadIdx.x;
    if (j >= NE) return;
    int e = edge_list[j];
    float d = dist[e];
    float inv = 1.f / d;
    float base = PI_ * d / RC_;
    float s1, c1;
    __sincosf(base, &s1, &c1);
    float twoc = c1 + c1;
    u16* rb = rbf_bf + (size_t)j * 32;
    float sprev = 0.f, scur = s1;
    #pragma unroll
    for (int k = 0; k < RBFN; k++) {
        rb[k] = f2b(scur * inv);
        float snext = twoc * scur - sprev;
        sprev = scur; scur = snext;
    }
    #pragma unroll
    for (int k = RBFN; k < 32; k++) rb[k] = 0;
    cut_p[j] = 0.5f * (c1 + 1.f) * (d < RC_ ? 1.f : 0.f);
    dst_p[j] = graph[2 * e + 1];
    sense_p[3 * j + 0] = sense[3 * e + 0];
    sense_p[3 * j + 1] = sense[3 * e + 1];
    sense_p[3 * j + 2] = sense[3 * e + 2];
}

// ---------------------------------------------------------------- fused node MLP (message path)
// Ob = (silu(A@W1^T + b1)) @ W2^T + b2.  A:(M,K1) bf16, W1:(128,K1), W2:(384,128).
// PACK layout (for edge gather): row of 384 u16 per node:
//   [0..255]  = (comp0, comp1) interleaved at f*2 + c   (c = gn>>7 for gn<256)
//   [256..383]= comp2 planar at 256 + (gn&127)
template<int K1, bool PACK>
__global__ __launch_bounds__(256) void mlp_kernel(const u16* __restrict__ A,
    const u16* __restrict__ W1, const float* __restrict__ b1,
    const u16* __restrict__ W2, const float* __restrict__ b2,
    u16* __restrict__ Ob, int M)
{
    __shared__ u16 As[64][KB + LPAD];
    __shared__ u16 Ws[128][KB + LPAD];
    __shared__ u16 T[64][KB + LPAD];
    const int bm = blockIdx.x * 64;
    const int tid = threadIdx.x;
    const int wave = tid >> 6, lane = tid & 63;
    const int wm  = (wave >> 1) * 32;
    const int wn1 = (wave & 1) * 64;
    const int wn  = (wave & 1) * 32;
    const int quad = lane >> 4, lr = lane & 15;
    const int r = tid >> 2, q = tid & 3;

    floatx4 acc1[2][4];
    #pragma unroll
    for (int i = 0; i < 2; i++)
        #pragma unroll
        for (int j = 0; j < 4; j++) acc1[i][j] = (floatx4)0.f;

    for (int ko = 0; ko < K1; ko += KB) {
        {
            int gm = bm + r;
            u16* dA = &As[r][q * 32];
            if (gm < M) {
                const u16* ap = A + (size_t)gm * K1 + ko + q * 32;
                #pragma unroll
                for (int x = 0; x < 32; x += 8)
                    *(bf16x8*)&dA[x] = *(const bf16x8*)(ap + x);
            } else {
                #pragma unroll
                for (int x = 0; x < 32; x += 8)
                    *(bf16x8*)&dA[x] = (bf16x8)0;
            }
            #pragma unroll
            for (int h = 0; h < 2; h++) {
                int wr = r + h * 64;
                const u16* wp = W1 + (size_t)wr * K1 + ko + q * 32;
                u16* dW = &Ws[wr][q * 32];
                #pragma unroll
                for (int x = 0; x < 32; x += 8)
                    *(bf16x8*)&dW[x] = *(const bf16x8*)(wp + x);
            }
        }
        __syncthreads();
        #pragma unroll
        for (int kk = 0; kk < KB; kk += 32) {
            bf16x8 a0 = *(const bf16x8*)&As[wm + lr     ][kk + quad * 8];
            bf16x8 a1 = *(const bf16x8*)&As[wm + 16 + lr][kk + quad * 8];
            #pragma unroll
            for (int j = 0; j < 4; j++) {
                bf16x8 b = *(const bf16x8*)&Ws[wn1 + j * 16 + lr][kk + quad * 8];
                acc1[0][j] = __builtin_amdgcn_mfma_f32_16x16x32_bf16(a0, b, acc1[0][j], 0, 0, 0);
                acc1[1][j] = __builtin_amdgcn_mfma_f32_16x16x32_bf16(a1, b, acc1[1][j], 0, 0, 0);
            }
        }
        __syncthreads();
    }
    #pragma unroll
    for (int i = 0; i < 2; i++) {
        #pragma unroll
        for (int j = 0; j < 4; j++) {
            int col = wn1 + j * 16 + lr;
            float bb = b1[col];
            #pragma unroll
            for (int rr = 0; rr < 4; rr++) {
                int row = wm + i * 16 + quad * 4 + rr;
                float v = acc1[i][j][rr] + bb;
                v = v / (1.f + __expf(-v));
                T[row][col] = f2b(v);
            }
        }
    }
    __syncthreads();

    for (int c0 = 0; c0 < F3; c0 += 64) {
        {
            const u16* wp = W2 + (size_t)(c0 + r) * KB + q * 32;
            u16* dW = &Ws[r][q * 32];
            #pragma unroll
            for (int x = 0; x < 32; x += 8)
                *(bf16x8*)&dW[x] = *(const bf16x8*)(wp + x);
        }
        __syncthreads();
        floatx4 acc2[2][2];
        #pragma unroll
        for (int i = 0; i < 2; i++)
            #pragma unroll
            for (int j = 0; j < 2; j++) acc2[i][j] = (floatx4)0.f;
        #pragma unroll
        for (int kk = 0; kk < KB; kk += 32) {
            bf16x8 a0 = *(const bf16x8*)&T[wm + lr     ][kk + quad * 8];
            bf16x8 a1 = *(const bf16x8*)&T[wm + 16 + lr][kk + quad * 8];
            bf16x8 b0 = *(const bf16x8*)&Ws[wn + lr     ][kk + quad * 8];
            bf16x8 b1 = *(const bf16x8*)&Ws[wn + 16 + lr][kk + quad * 8];
            acc2[0][0] = __builtin_amdgcn_mfma_f32_16x16x32_bf16(a0, b0, acc2[0][0], 0, 0, 0);
            acc2[0][1] = __builtin_amdgcn_mfma_f32_16x16x32_bf16(a0, b1, acc2[0][1], 0, 0, 0);
            acc2[1][0] = __builtin_amdgcn_mfma_f32_16x16x32_bf16(a1, b0, acc2[1][0], 0, 0, 0);
            acc2[1][1] = __builtin_amdgcn_mfma_f32_16x16x32_bf16(a1, b1, acc2[1][1], 0, 0, 0);
        }
        #pragma unroll
        for (int i = 0; i < 2; i++) {
            #pragma unroll
            for (int j = 0; j < 2; j++) {
                int gn = c0 + wn + j * 16 + lr;
                float bb = b2[gn];
                #pragma unroll
                for (int rr = 0; rr < 4; rr++) {
                    int gm = bm + wm + i * 16 + quad * 4 + rr;
                    if (gm < M) {
                        u16 val = f2b(acc2[i][j][rr] + bb);
                        if (PACK) {
                            int off = (gn < 256) ? ((gn & 127) * 2 + (gn >> 7))
                                                 : (256 + (gn & 127));
                            Ob[(size_t)gm * F3 + off] = val;
                        } else {
                            Ob[(size_t)gm * F3 + gn] = val;
                        }
                    }
                }
            }
        }
        __syncthreads();
    }
}

// Dual GEMM: U = A@Wu^T, V = A@Wv^T (K=128, Nc=128). bf16 outs.
__global__ __launch_bounds__(256) void gemm_uv(const u16* __restrict__ A,
    const u16* __restrict__ Wu, const u16* __restrict__ Wv,
    u16* __restrict__ U, u16* __restrict__ V, int M)
{
    __shared__ u16 As[64][KB + LPAD];
    __shared__ u16 Bu[64][KB + LPAD];
    __shared__ u16 Bv[64][KB + LPAD];
    const int bm = blockIdx.x * 64;
    const int bn = blockIdx.y * 64;
    const int tid = threadIdx.x;
    const int r = tid >> 2;
    const int q = tid & 3;
    const int wave = tid >> 6;
    const int lane = tid & 63;
    const int wm = (wave >> 1) * 32;
    const int wn = (wave & 1) * 32;
    const int quad = lane >> 4;
    const int lr = lane & 15;

    floatx4 au[2][2], av[2][2];
    #pragma unroll
    for (int i = 0; i < 2; i++)
        #pragma unroll
        for (int j = 0; j < 2; j++) { au[i][j] = (floatx4)0.f; av[i][j] = (floatx4)0.f; }

    {
        int gm = bm + r;
        u16* dA = &As[r][q * 32];
        if (gm < M) {
            const u16* ap = A + (size_t)gm * KB + q * 32;
            #pragma unroll
            for (int x = 0; x < 32; x += 8)
                *(bf16x8*)&dA[x] = *(const bf16x8*)(ap + x);
        } else {
            #pragma unroll
            for (int x = 0; x < 32; x += 8)
                *(bf16x8*)&dA[x] = (bf16x8)0;
        }
        int gn = bn + r;
        const u16* up = Wu + (size_t)gn * KB + q * 32;
        const u16* vp = Wv + (size_t)gn * KB + q * 32;
        u16* dU = &Bu[r][q * 32];
        u16* dV = &Bv[r][q * 32];
        #pragma unroll
        for (int x = 0; x < 32; x += 8) {
            *(bf16x8*)&dU[x] = *(const bf16x8*)(up + x);
            *(bf16x8*)&dV[x] = *(const bf16x8*)(vp + x);
        }
    }
    __syncthreads();
    #pragma unroll
    for (int kk = 0; kk < KB; kk += 32) {
        bf16x8 a0 = *(const bf16x8*)&As[wm + lr     ][kk + quad * 8];
        bf16x8 a1 = *(const bf16x8*)&As[wm + 16 + lr][kk + quad * 8];
        bf16x8 u0 = *(const bf16x8*)&Bu[wn + lr     ][kk + quad * 8];
        bf16x8 u1 = *(const bf16x8*)&Bu[wn + 16 + lr][kk + quad * 8];
        bf16x8 v0 = *(const bf16x8*)&Bv[wn + lr     ][kk + quad * 8];
        bf16x8 v1 = *(const bf16x8*)&Bv[wn + 16 + lr][kk + quad * 8];
        au[0][0] = __builtin_amdgcn_mfma_f32_16x16x32_bf16(a0, u0, au[0][0], 0, 0, 0);
        au[0][1] = __builtin_amdgcn_mfma_f32_16x16x32_bf16(a0, u1, au[0][1], 0, 0, 0);
        au[1][0] = __builtin_amdgcn_mfma_f32_16x16x32_bf16(a1, u0, au[1][0], 0, 0, 0);
        au[1][1] = __builtin_amdgcn_mfma_f32_16x16x32_bf16(a1, u1, au[1][1], 0, 0, 0);
        av[0][0] = __builtin_amdgcn_mfma_f32_16x16x32_bf16(a0, v0, av[0][0], 0, 0, 0);
        av[0][1] = __builtin_amdgcn_mfma_f32_16x16x32_bf16(a0, v1, av[0][1], 0, 0, 0);
        av[1][0] = __builtin_amdgcn_mfma_f32_16x16x32_bf16(a1, v0, av[1][0], 0, 0, 0);
        av[1][1] = __builtin_amdgcn_mfma_f32_16x16x32_bf16(a1, v1, av[1][1], 0, 0, 0);
    }
    #pragma unroll
    for (int i = 0; i < 2; i++) {
        #pragma unroll
        for (int j = 0; j < 2; j++) {
            int gn = bn + wn + j * 16 + lr;
            #pragma unroll
            for (int rr = 0; rr < 4; rr++) {
                int gm = bm + wm + i * 16 + quad * 4 + rr;
                if (gm < M) {
                    U[(size_t)gm * FD + gn] = f2b(au[i][j][rr]);
                    V[(size_t)gm * FD + gn] = f2b(av[i][j][rr]);
                }
            }
        }
    }
}

// ---------------------------------------------------------------- edge aggregate (MFMA dist_rep)
// 256 threads/node — PROVEN 138µs form, do not modify. Per 16-edge tile: dist_rep via 24
// MFMAs -> planar bf16 sdrep in LDS; gathers via packed (pair + planar) bf16 rows;
// serial runtime-bound nh loop (unroll / pair-gather / 512-thread variants all measured slower).
__global__ __launch_bounds__(256) void edge_mfma_kernel(
    const u16* __restrict__ rbf_bf, const float* __restrict__ cut_p,
    const float* __restrict__ sense_p, const int* __restrict__ dst_p,
    const u16* __restrict__ ewb, const float* __restrict__ eb,
    const u16* __restrict__ a_pk, const float* __restrict__ s_in,
    const float* __restrict__ v_in, const u16* __restrict__ v_pk,
    const int* __restrict__ row_ptr,
    float* __restrict__ s_out, u16* __restrict__ s_obf,
    float* __restrict__ v_out, u16* __restrict__ v_obf)
{
    __shared__ u16   sdrep[16 * SDS];   // planar bf16: [e][col] — 12.25 KB
    __shared__ float scut[16];
    __shared__ float ssen[16][4];
    __shared__ int   sdst[16];
    __shared__ float red[4 * 128];

    const int n = blockIdx.x;
    const int tid = threadIdx.x;
    const int wave = tid >> 6;
    const int lane = tid & 63;
    const int quad = lane >> 4;
    const int lr = lane & 15;
    const int f = tid & 127;
    const int half = tid >> 7;

    int beg = row_ptr[n], end = row_ptr[n + 1];
    float accs = 0.f, accv0 = 0.f, accv1 = 0.f, accv2 = 0.f;

    for (int t0 = beg; t0 < end; t0 += 16) {
        int cnt = end - t0; if (cnt > 16) cnt = 16;
        __syncthreads();   // previous tile fully consumed
        if (tid < 16) {
            scut[tid] = (tid < cnt) ? cut_p[t0 + tid] : 0.f;
            sdst[tid] = (tid < cnt) ? dst_p[t0 + tid] : 0;
        }
        if (tid >= 64 && tid < 64 + 3 * cnt) {
            int x = tid - 64;
            ssen[x / 3][x % 3] = sense_p[3 * t0 + x];
        }
        // MFMA: A = rbf rows (lane m=lr = edge), B = ew rows (6 col-tiles/wave)
        bf16x8 afrag;
        int ge = t0 + lr;
        if (ge < end) afrag = *(const bf16x8*)&rbf_bf[(size_t)ge * 32 + quad * 8];
        else          afrag = (bf16x8)0;
        floatx4 dacc[6];
        #pragma unroll
        for (int nt = 0; nt < 6; nt++) {
            int nrow = (wave * 6 + nt) * 16 + lr;
            bf16x8 bfrag = *(const bf16x8*)&ewb[(size_t)nrow * 32 + quad * 8];
            dacc[nt] = __builtin_amdgcn_mfma_f32_16x16x32_bf16(afrag, bfrag, (floatx4)0.f, 0, 0, 0);
        }
        __syncthreads();   // staged scalars visible
        // epilogue: (d + eb) * cut -> planar bf16 sdrep; C/D layout col=lr, row(edge)=quad*4+rr
        #pragma unroll
        for (int nt = 0; nt < 6; nt++) {
            int ncol = (wave * 6 + nt) * 16 + lr;
            float ebn = eb[ncol];
            #pragma unroll
            for (int rr = 0; rr < 4; rr++) {
                int e = quad * 4 + rr;
                sdrep[e * SDS + ncol] = f2b((dacc[nt][rr] + ebn) * scut[e]);
            }
        }
        __syncthreads();   // sdrep ready
        // aggregation: half h handles up to 8 edges
        int nh = cnt - half * 8; if (nh > 8) nh = 8;
        for (int k = 0; k < nh; k++) {
            int e = half * 8 + k;
            int dst = sdst[e];
            const u16* sr = &sdrep[e * SDS];
            float drv = b2f(sr[f]);
            float drs = b2f(sr[FD + f]);
            float drd = b2f(sr[2 * FD + f]);
            const u16* ar = a_pk + (size_t)dst * F3;
            u32 ap = *(const u32*)(ar + f * 2);
            float rv = b2f((u16)(ap & 0xffff)) * drv;
            float rs = b2f((u16)(ap >> 16))    * drs;
            float rd = b2f(ar[256 + f])        * drd;
            accs += rs;
            const u16* vr = v_pk + (size_t)dst * F3;
            u32 vp = *(const u32*)(vr + f * 2);
            accv0 += b2f((u16)(vp & 0xffff)) * rv + ssen[e][0] * rd;
            accv1 += b2f((u16)(vp >> 16))    * rv + ssen[e][1] * rd;
            accv2 += b2f(vr[256 + f])        * rv + ssen[e][2] * rd;
        }
    }
    // combine halves, write
    __syncthreads();
    if (half == 1) {
        red[f] = accs; red[128 + f] = accv0; red[256 + f] = accv1; red[384 + f] = accv2;
    }
    __syncthreads();
    if (half == 0) {
        accs  += red[f];       accv0 += red[128 + f];
        accv1 += red[256 + f]; accv2 += red[384 + f];
        int nb = n * FD + f;
        float so = s_in[nb] + 2.f * accs;
        s_out[nb] = so; s_obf[nb] = f2b(so);
        int vb = n * F3 + f;
        float w0 = v_in[vb]           + 2.f * accv0;
        float w1 = v_in[vb + FD]      + 2.f * accv1;
        float w2 = v_in[vb + 2 * FD]  + 2.f * accv2;
        v_out[vb]          = w0; v_obf[vb]          = f2b(w0);
        v_out[vb + FD]     = w1; v_obf[vb + FD]     = f2b(w1);
        v_out[vb + 2 * FD] = w2; v_obf[vb + 2 * FD] = f2b(w2);
    }
}

// ---------------------------------------------------------------- fused mlp2 + build_h + update
// a2 = (silu(h@aw1^T+ab1))@aw2^T+ab2 with h = [s_mid, |Vv|] built in A-staging (no h_bf).
// GEMM2 chunks reordered (avv,asv,ass per f-half); avv/asv parked in regs (identical lane
// mapping across chunks); ass chunk performs the node update inline (no a2_bf).
__global__ __launch_bounds__(256) void mlp2_update_kernel(
    const u16* __restrict__ sbf_mid, const float* __restrict__ s_mid,
    const float* __restrict__ v_mid,
    const u16* __restrict__ Uv, const u16* __restrict__ Vv,
    const u16* __restrict__ W1, const float* __restrict__ b1,
    const u16* __restrict__ W2, const float* __restrict__ b2,
    float* __restrict__ s_out, u16* __restrict__ s_obf,
    float* __restrict__ v_out, u16* __restrict__ v_pk, int M)
{
    __shared__ u16 As[64][KB + LPAD];
    __shared__ u16 Ws[128][KB + LPAD];
    __shared__ u16 T[64][KB + LPAD];
    const int bm = blockIdx.x * 64;
    const int tid = threadIdx.x;
    const int wave = tid >> 6, lane = tid & 63;
    const int wm  = (wave >> 1) * 32;
    const int wn1 = (wave & 1) * 64;
    const int wn  = (wave & 1) * 32;
    const int quad = lane >> 4, lr = lane & 15;
    const int r = tid >> 2, q = tid & 3;

    floatx4 acc1[2][4];
    #pragma unroll
    for (int i = 0; i < 2; i++)
        #pragma unroll
        for (int j = 0; j < 4; j++) acc1[i][j] = (floatx4)0.f;

    // ---- GEMM1, ko chunk 0: A cols = s_mid bf16
    {
        int gm = bm + r;
        u16* dA = &As[r][q * 32];
        if (gm < M) {
            const u16* ap = sbf_mid + (size_t)gm * FD + q * 32;
            #pragma unroll
            for (int x = 0; x < 32; x += 8)
                *(bf16x8*)&dA[x] = *(const bf16x8*)(ap + x);
        } else {
            #pragma unroll
            for (int x = 0; x < 32; x += 8)
                *(bf16x8*)&dA[x] = (bf16x8)0;
        }
        #pragma unroll
        for (int h = 0; h < 2; h++) {
            int wr = r + h * 64;
            const u16* wp = W1 + (size_t)wr * F2 + q * 32;
            u16* dW = &Ws[wr][q * 32];
            #pragma unroll
            for (int x = 0; x < 32; x += 8)
                *(bf16x8*)&dW[x] = *(const bf16x8*)(wp + x);
        }
    }
    __syncthreads();
    #pragma unroll
    for (int kk = 0; kk < KB; kk += 32) {
        bf16x8 a0 = *(const bf16x8*)&As[wm + lr     ][kk + quad * 8];
        bf16x8 a1 = *(const bf16x8*)&As[wm + 16 + lr][kk + quad * 8];
        #pragma unroll
        for (int j = 0; j < 4; j++) {
            bf16x8 b = *(const bf16x8*)&Ws[wn1 + j * 16 + lr][kk + quad * 8];
            acc1[0][j] = __builtin_amdgcn_mfma_f32_16x16x32_bf16(a0, b, acc1[0][j], 0, 0, 0);
            acc1[1][j] = __builtin_amdgcn_mfma_f32_16x16x32_bf16(a1, b, acc1[1][j], 0, 0, 0);
        }
    }
    __syncthreads();
    // ---- GEMM1, ko chunk 1: A cols = |Vv| computed inline (build_h fused)
    {
        int gm = bm + r;
        u16* dA = &As[r][q * 32];
        if (gm < M) {
            const u16* vvp = Vv + (size_t)gm * F3 + q * 32;
            bf16x8 c0[4], c1[4], c2[4];
            #pragma unroll
            for (int t = 0; t < 4; t++) {
                c0[t] = *(const bf16x8*)(vvp + t * 8);
                c1[t] = *(const bf16x8*)(vvp + FD + t * 8);
                c2[t] = *(const bf16x8*)(vvp + 2 * FD + t * 8);
            }
            #pragma unroll
            for (int t = 0; t < 4; t++) {
                #pragma unroll
                for (int x = 0; x < 8; x++) {
                    float a = b2f((u16)c0[t][x]);
                    float b = b2f((u16)c1[t][x]);
                    float c = b2f((u16)c2[t][x]);
                    dA[t * 8 + x] = f2b(sqrtf(a * a + b * b + c * c));
                }
            }
        } else {
            #pragma unroll
            for (int x = 0; x < 32; x += 8)
                *(bf16x8*)&dA[x] = (bf16x8)0;
        }
        #pragma unroll
        for (int h = 0; h < 2; h++) {
            int wr = r + h * 64;
            const u16* wp = W1 + (size_t)wr * F2 + KB + q * 32;
            u16* dW = &Ws[wr][q * 32];
            #pragma unroll
            for (int x = 0; x < 32; x += 8)
                *(bf16x8*)&dW[x] = *(const bf16x8*)(wp + x);
        }
    }
    __syncthreads();
    #pragma unroll
    for (int kk = 0; kk < KB; kk += 32) {
        bf16x8 a0 = *(const bf16x8*)&As[wm + lr     ][kk + quad * 8];
        bf16x8 a1 = *(const bf16x8*)&As[wm + 16 + lr][kk + quad * 8];
        #pragma unroll
        for (int j = 0; j < 4; j++) {
            bf16x8 b = *(const bf16x8*)&Ws[wn1 + j * 16 + lr][kk + quad * 8];
            acc1[0][j] = __builtin_amdgcn_mfma_f32_16x16x32_bf16(a0, b, acc1[0][j], 0, 0, 0);
            acc1[1][j] = __builtin_amdgcn_mfma_f32_16x16x32_bf16(a1, b, acc1[1][j], 0, 0, 0);
        }
    }
    __syncthreads();
    // T = silu(acc1 + b1) as bf16
    #pragma unroll
    for (int i = 0; i < 2; i++) {
        #pragma unroll
        for (int j = 0; j < 4; j++) {
            int col = wn1 + j * 16 + lr;
            float bb = b1[col];
            #pragma unroll
            for (int rr = 0; rr < 4; rr++) {
                int row = wm + i * 16 + quad * 4 + rr;
                float v = acc1[i][j][rr] + bb;
                v = v / (1.f + __expf(-v));
                T[row][col] = f2b(v);
            }
        }
    }
    __syncthreads();

    // ---- GEMM2: chunk order (avv, asv, ass) per f-half; update fused into ass epilogue
    float avvr[2][2][4], asvr[2][2][4];
    #pragma unroll
    for (int part = 0; part < 2; part++) {
        #pragma unroll
        for (int piece = 0; piece < 3; piece++) {
            const int c0 = piece * 128 + part * 64;
            {
                const u16* wp = W2 + (size_t)(c0 + r) * KB + q * 32;
                u16* dW = &Ws[r][q * 32];
                #pragma unroll
                for (int x = 0; x < 32; x += 8)
                    *(bf16x8*)&dW[x] = *(const bf16x8*)(wp + x);
            }
            __syncthreads();
            floatx4 acc2[2][2];
            #pragma unroll
            for (int i = 0; i < 2; i++)
                #pragma unroll
                for (int j = 0; j < 2; j++) acc2[i][j] = (floatx4)0.f;
            #pragma unroll
            for (int kk = 0; kk < KB; kk += 32) {
                bf16x8 a0 = *(const bf16x8*)&T[wm + lr     ][kk + quad * 8];
                bf16x8 a1 = *(const bf16x8*)&T[wm + 16 + lr][kk + quad * 8];
                bf16x8 b0 = *(const bf16x8*)&Ws[wn + lr     ][kk + quad * 8];
                bf16x8 b1 = *(const bf16x8*)&Ws[wn + 16 + lr][kk + quad * 8];
                acc2[0][0] = __builtin_amdgcn_mfma_f32_16x16x32_bf16(a0, b0, acc2[0][0], 0, 0, 0);
                acc2[0][1] = __builtin_amdgcn_mfma_f32_16x16x32_bf16(a0, b1, acc2[0][1], 0, 0, 0);
                acc2[1][0] = __builtin_amdgcn_mfma_f32_16x16x32_bf16(a1, b0, acc2[1][0], 0, 0, 0);
                acc2[1][1] = __builtin_amdgcn_mfma_f32_16x16x32_bf16(a1, b1, acc2[1][1], 0, 0, 0);
            }
            if (piece == 0) {
                #pragma unroll
                for (int i = 0; i < 2; i++)
                    #pragma unroll
                    for (int j = 0; j < 2; j++) {
                        int gn = c0 + wn + j * 16 + lr;
                        float bb = b2[gn];
                        #pragma unroll
                        for (int rr = 0; rr < 4; rr++)
                            avvr[i][j][rr] = acc2[i][j][rr] + bb;
                    }
            } else if (piece == 1) {
                #pragma unroll
                for (int i = 0; i < 2; i++)
                    #pragma unroll
                    for (int j = 0; j < 2; j++) {
                        int gn = c0 + wn + j * 16 + lr;
                        float bb = b2[gn];
                        #pragma unroll
                        for (int rr = 0; rr < 4; rr++)
                            asvr[i][j][rr] = acc2[i][j][rr] + bb;
                    }
            } else {
                // ass chunk: full node update (fused update_kernel)
                #pragma unroll
                for (int i = 0; i < 2; i++) {
                    #pragma unroll
                    for (int j = 0; j < 2; j++) {
                        int gn = c0 + wn + j * 16 + lr;
                        int f  = gn - 256;          // = part*64 + wn + j*16 + lr
                        float bb = b2[gn];
                        #pragma unroll
                        for (int rr = 0; rr < 4; rr++) {
                            int gm = bm + wm + i * 16 + quad * 4 + rr;
                            if (gm < M) {
                                float ass = acc2[i][j][rr] + bb;
                                float asv = asvr[i][j][rr];
                                float avv = avvr[i][j][rr];
                                int vb = gm * F3 + f;
                                float u0 = b2f(Uv[vb]);
                                float u1 = b2f(Uv[vb + FD]);
                                float u2 = b2f(Uv[vb + 2 * FD]);
                                float w0 = b2f(Vv[vb]);
                                float w1 = b2f(Vv[vb + FD]);
                                float w2 = b2f(Vv[vb + 2 * FD]);
                                float dot = u0 * w0 + u1 * w1 + u2 * w2;
                                int nb = gm * FD + f;
                                float so = s_mid[nb] + ass + asv * dot;
                                s_out[nb] = so; s_obf[nb] = f2b(so);
                                float y0 = v_mid[vb]          + avv * u0;
                                float y1 = v_mid[vb + FD]     + avv * u1;
                                float y2 = v_mid[vb + 2 * FD] + avv * u2;
                                v_out[vb]          = y0;
                                v_out[vb + FD]     = y1;
                                v_out[vb + 2 * FD] = y2;
                                char* vpb = (char*)v_pk + (size_t)gm * (2 * F3);
                                *(u32*)(vpb + 4 * f) = pack2(y0, y1);
                                *(u16*)(vpb + 512 + 2 * f) = f2b(y2);
                            }
                        }
                    }
                }
            }
            __syncthreads();
        }
    }
}

// ---------------------------------------------------------------- fused final head
// t = silu(s@ow1^T + ob1); nodeval[n] = t[n,:]·ow2 + ob2.  One block = 64 nodes, full K=Nc=128.
__global__ __launch_bounds__(256) void head_kernel(const u16* __restrict__ A,
    const u16* __restrict__ W1, const float* __restrict__ b1,
    const float* __restrict__ ow2, const float* __restrict__ ob2,
    float* __restrict__ nodeval)
{
    __shared__ u16 As[64][KB + LPAD];
    __shared__ u16 Ws[128][KB + LPAD];
    __shared__ float T[64][KB + 4];
    __shared__ float ow2s[KB];
    const int bm = blockIdx.x * 64;
    const int tid = threadIdx.x;
    const int wave = tid >> 6, lane = tid & 63;
    const int wm  = (wave >> 1) * 32;
    const int wn1 = (wave & 1) * 64;
    const int quad = lane >> 4, lr = lane & 15;
    const int r = tid >> 2, q = tid & 3;

    if (tid < KB) ow2s[tid] = ow2[tid];

    floatx4 acc1[2][4];
    #pragma unroll
    for (int i = 0; i < 2; i++)
        #pragma unroll
        for (int j = 0; j < 4; j++) acc1[i][j] = (floatx4)0.f;

    {
        int gm = bm + r;
        u16* dA = &As[r][q * 32];
        if (gm < NN) {
            const u16* ap = A + (size_t)gm * KB + q * 32;
            #pragma unroll
            for (int x = 0; x < 32; x += 8)
                *(bf16x8*)&dA[x] = *(const bf16x8*)(ap + x);
        } else {
            #pragma unroll
            for (int x = 0; x < 32; x += 8)
                *(bf16x8*)&dA[x] = (bf16x8)0;
        }
        #pragma unroll
        for (int h = 0; h < 2; h++) {
            int wr = r + h * 64;
            const u16* wp = W1 + (size_t)wr * KB + q * 32;
            u16* dW = &Ws[wr][q * 32];
            #pragma unroll
            for (int x = 0; x < 32; x += 8)
                *(bf16x8*)&dW[x] = *(const bf16x8*)(wp + x);
        }
    }
    __syncthreads();
    #pragma unroll
    for (int kk = 0; kk < KB; kk += 32) {
        bf16x8 a0 = *(const bf16x8*)&As[wm + lr     ][kk + quad * 8];
        bf16x8 a1 = *(const bf16x8*)&As[wm + 16 + lr][kk + quad * 8];
        #pragma unroll
        for (int j = 0; j < 4; j++) {
            bf16x8 b = *(const bf16x8*)&Ws[wn1 + j * 16 + lr][kk + quad * 8];
            acc1[0][j] = __builtin_amdgcn_mfma_f32_16x16x32_bf16(a0, b, acc1[0][j], 0, 0, 0);
            acc1[1][j] = __builtin_amdgcn_mfma_f32_16x16x32_bf16(a1, b, acc1[1][j], 0, 0, 0);
        }
    }
    #pragma unroll
    for (int i = 0; i < 2; i++) {
        #pragma unroll
        for (int j = 0; j < 4; j++) {
            int col = wn1 + j * 16 + lr;
            float bb = b1[col];
            #pragma unroll
            for (int rr = 0; rr < 4; rr++) {
                int row = wm + i * 16 + quad * 4 + rr;
                float v = acc1[i][j][rr] + bb;
                v = v / (1.f + __expf(-v));
                T[row][col] = v;
            }
        }
    }
    __syncthreads();
    // dot with ow2: 4 threads per node, 32 cols each, shfl-reduce
    int nl = tid >> 2, seg = tid & 3;
    float v = 0.f;
    #pragma unroll
    for (int x = 0; x < 32; x++) {
        int col = seg * 32 + x;
        v += T[nl][col] * ow2s[col];
    }
    v += __shfl_down(v, 2);
    v += __shfl_down(v, 1);
    if (seg == 0) {
        int gm = bm + nl;
        if (gm < NN) nodeval[gm] = v + ob2[0];
    }
}

__global__ __launch_bounds__(1024) void mol_reduce_kernel(const float* __restrict__ nodeval,
    const int* __restrict__ gidx, float* __restrict__ out)
{
    __shared__ float mol[NMOL];
    int tid = threadIdx.x;
    if (tid < NMOL) mol[tid] = 0.f;
    __syncthreads();
    int cur = -1; float acc = 0.f;
    for (int x = tid; x < NN; x += 1024) {
        int g = gidx[x];
        float v = nodeval[x];
        if (g != cur) {
            if (cur >= 0) atomicAdd(&mol[cur], acc);
            cur = g; acc = v;
        } else acc += v;
    }
    if (cur >= 0) atomicAdd(&mol[cur], acc);
    __syncthreads();
    if (tid < NMOL) out[tid] = mol[tid];
}

// ---------------------------------------------------------------- launch
extern "C" void kernel_launch(void* const* d_in, const int* in_sizes, int n_in,
                              void* d_out, int out_size, void* d_ws, size_t ws_size,
                              hipStream_t stream)
{
    const int*   z     = (const int*)d_in[0];
    const int*   graph = (const int*)d_in[1];
    const float* dist  = (const float*)d_in[2];
    const float* sense = (const float*)d_in[3];
    const int*   gidx  = (const int*)d_in[4];
    const float* emb   = (const float*)d_in[5];
    const float* mw1   = (const float*)d_in[6];
    const float* mb1   = (const float*)d_in[7];
    const float* mw2   = (const float*)d_in[8];
    const float* mb2   = (const float*)d_in[9];
    const float* ew    = (const float*)d_in[10];
    const float* eb    = (const float*)d_in[11];
    const float* uw    = (const float*)d_in[12];
    const float* vw    = (const float*)d_in[13];
    const float* aw1   = (const float*)d_in[14];
    const float* ab1   = (const float*)d_in[15];
    const float* aw2   = (const float*)d_in[16];
    const float* ab2   = (const float*)d_in[17];
    const float* ow1   = (const float*)d_in[18];
    const float* ob1   = (const float*)d_in[19];
    const float* ow2   = (const float*)d_in[20];
    const float* ob2   = (const float*)d_in[21];
    float* out = (float*)d_out;

    // ---- workspace carve-up ----
    float* W = (float*)d_ws;
    float* s_a    = W; W += (size_t)NN * FD;
    float* s_b    = W; W += (size_t)NN * FD;
    float* v_a    = W; W += (size_t)NN * F3;
    float* v_b    = W; W += (size_t)NN * F3;
    float* cut_p  = W; W += (size_t)NE;
    float* sns_p  = W; W += (size_t)NE * 3;
    float* nodeval= W; W += (size_t)NN;
    u16* U = (u16*)W;
    u16* sbf_a = U; U += (size_t)NN * FD;
    u16* sbf_b = U; U += (size_t)NN * FD;
    u16* vbf_b = U; U += (size_t)NN * F3;
    u16* a_pk  = U; U += (size_t)NN * F3;
    u16* v_pk  = U; U += (size_t)NN * F3;
    u16* h_bf  = U; U += (size_t)NN * F2;   // unused (kept for layout stability)
    u16* a2_bf = U; U += (size_t)NN * F3;   // unused (kept for layout stability)
    u16* Uv_bf = U; U += (size_t)NN * F3;
    u16* Vv_bf = U; U += (size_t)NN * F3;
    u16* rbf_bf= U; U += (size_t)NE * 32;
    u16* ewb   = U; U += (size_t)NITER * F3 * 32;
    u16* wb    = U; U += 557056;
    int* ip = (int*)U;
    int* row_ptr   = ip; ip += NN + 1;
    int* cnt       = ip; ip += NN;
    int* cursor    = ip; ip += NN;
    int* edge_list = ip; ip += NE;
    int* dst_p     = ip; ip += NE;

    // bf16 weight table offsets
    u16* wb_mw1 = wb;            // 3*128*128
    u16* wb_mw2 = wb + 49152;    // 3*384*128
    u16* wb_uw  = wb + 196608;   // 3*128*128
    u16* wb_vw  = wb + 245760;   // 3*128*128
    u16* wb_aw1 = wb + 294912;   // 3*128*256
    u16* wb_aw2 = wb + 393216;   // 3*384*128
    u16* wb_ow1 = wb + 540672;   // 128*128
    const int WTOT = 557056;

    const int TB = 256;
    dim3 b256(TB);

    // --- precompute ---
    cvt_w_kernel<<<dim3((WTOT + TB - 1) / TB), b256, 0, stream>>>(
        mw1, 49152, mw2, 147456, uw, 49152, vw, 49152, aw1, 98304, aw2, 147456,
        ow1, 16384, wb);
    cvt_ew_kernel<<<dim3((NITER * F3 * 32 + TB - 1) / TB), b256, 0, stream>>>(ew, ewb);
    init_kernel<<<dim3((NN * F3 + TB - 1) / TB), b256, 0, stream>>>(
        z, emb, s_a, sbf_a, v_a, (int*)v_pk);
    zero_i_kernel<<<dim3((NN + TB - 1) / TB), b256, 0, stream>>>(cnt, NN);
    csr_count_kernel<<<dim3((NE + TB - 1) / TB), b256, 0, stream>>>(graph, cnt);
    csr_scan_kernel<<<dim3(1), dim3(1024), 0, stream>>>(cnt, row_ptr, cursor);
    csr_scatter_kernel<<<dim3((NE + TB - 1) / TB), b256, 0, stream>>>(graph, cursor, edge_list);
    edge_stream_kernel<<<dim3((NE + TB - 1) / TB), b256, 0, stream>>>(
        edge_list, graph, dist, sense, rbf_bf, cut_p, sns_p, dst_p);

    dim3 gM((NN + 63) / 64);                   // fused MLPs / head
    dim3 gV2((3 * NN + 63) / 64, FD / 64);     // M=3N, Nc=128

    for (int i = 0; i < NITER; i++) {
        mlp_kernel<128, true><<<gM, b256, 0, stream>>>(sbf_a,
            wb_mw1 + (size_t)i * FD * FD, mb1 + (size_t)i * FD,
            wb_mw2 + (size_t)i * F3 * FD, mb2 + (size_t)i * F3, a_pk, NN);
        edge_mfma_kernel<<<dim3(NN), b256, 0, stream>>>(
            rbf_bf, cut_p, sns_p, dst_p,
            ewb + (size_t)i * F3 * 32, eb + (size_t)i * F3,
            a_pk, s_a, v_a, v_pk, row_ptr, s_b, sbf_b, v_b, vbf_b);
        gemm_uv<<<gV2, b256, 0, stream>>>(vbf_b, wb_uw + (size_t)i * FD * FD,
            wb_vw + (size_t)i * FD * FD, Uv_bf, Vv_bf, 3 * NN);
        mlp2_update_kernel<<<gM, b256, 0, stream>>>(
            sbf_b, s_b, v_b, Uv_bf, Vv_bf,
            wb_aw1 + (size_t)i * FD * F2, ab1 + (size_t)i * FD,
            wb_aw2 + (size_t)i * F3 * FD, ab2 + (size_t)i * F3,
            s_a, sbf_a, v_a, v_pk, NN);
    }

    head_kernel<<<gM, b256, 0, stream>>>(sbf_a, wb_ow1, ob1, ow2, ob2, nodeval);
    mol_reduce_kernel<<<dim3(1), dim3(1024), 0, stream>>>(nodeval, gidx, out);
}

// Round 6
// 868.539 us; speedup vs baseline: 1.1371x; 1.0052x over previous
//
#include <hip/hip_runtime.h>
#include <math.h>

// Problem constants
#define NN 20000
#define NE 320000
#define FD 128
#define RBFN 20
#define RC_ 5.0f
#define NITER 3
#define NMOL 64
#define F3 384
#define F2 256
#define PI_ 3.14159265358979323846f
#define KB 128
#define LPAD 8
#define SDS 392   // u16 stride per sdrep edge row (384 + 8 pad)

typedef __attribute__((ext_vector_type(8))) short  bf16x8;
typedef __attribute__((ext_vector_type(4))) float  floatx4;
typedef unsigned short u16;
typedef unsigned int   u32;

__device__ __forceinline__ u16 f2b(float x) {
    union { float f; unsigned int u; } v; v.f = x;
    unsigned int u = v.u;
    return (u16)((u + 0x7fffu + ((u >> 16) & 1u)) >> 16);   // RNE
}
__device__ __forceinline__ float b2f(u16 x) {
    union { unsigned int u; float f; } v; v.u = ((unsigned int)x) << 16;
    return v.f;
}
__device__ __forceinline__ float blo(u32 w) {
    union { unsigned int u; float f; } v; v.u = w << 16; return v.f;
}
__device__ __forceinline__ float bhi(u32 w) {
    union { unsigned int u; float f; } v; v.u = w & 0xffff0000u; return v.f;
}
__device__ __forceinline__ u32 pack2(float a, float b) {
    return (u32)f2b(a) | ((u32)f2b(b) << 16);
}

// ---------------------------------------------------------------- fused one-time init:
// weight cvt (7 tables) + ew cvt + embed + v/v_pk/cnt zeroing, all independent ranges.
__global__ __launch_bounds__(256) void init_all_kernel(
    const float* s0, int n0, const float* s1, int n1, const float* s2, int n2,
    const float* s3, int n3, const float* s4, int n4, const float* s5, int n5,
    const float* s6, int n6, u16* __restrict__ wdst,
    const float* __restrict__ ew, u16* __restrict__ ewb,
    const int* __restrict__ z, const float* __restrict__ emb,
    float* __restrict__ s, u16* __restrict__ sbf,
    float* __restrict__ v_a, int* __restrict__ v_pk_i, int* __restrict__ cnt)
{
    int idx = blockIdx.x * 256 + threadIdx.x;
    if (idx < NN * F3) v_a[idx] = 0.f;
    if (idx < NN * F3 / 2) v_pk_i[idx] = 0;
    if (idx < NN) cnt[idx] = 0;
    if (idx < NN * FD) {
        int n = idx >> 7, f = idx & 127;
        float v = emb[z[n] * FD + f];
        s[idx] = v; sbf[idx] = f2b(v);
    }
    if (idx < NITER * F3 * 32) {
        int k = idx & 31;
        int row = idx >> 5;
        ewb[idx] = (k < RBFN) ? f2b(ew[row * RBFN + k]) : (u16)0;
    }
    {
        int w = idx;
        u16* dst = wdst;
        if (w < n0) { dst[w] = f2b(s0[w]); return; } w -= n0; dst += n0;
        if (w < n1) { dst[w] = f2b(s1[w]); return; } w -= n1; dst += n1;
        if (w < n2) { dst[w] = f2b(s2[w]); return; } w -= n2; dst += n2;
        if (w < n3) { dst[w] = f2b(s3[w]); return; } w -= n3; dst += n3;
        if (w < n4) { dst[w] = f2b(s4[w]); return; } w -= n4; dst += n4;
        if (w < n5) { dst[w] = f2b(s5[w]); return; } w -= n5; dst += n5;
        if (w < n6) { dst[w] = f2b(s6[w]); }
    }
}

// ---------------------------------------------------------------- CSR build
__global__ __launch_bounds__(256) void csr_count_kernel(const int* __restrict__ graph,
    int* __restrict__ cnt)
{
    int e = blockIdx.x * 256 + threadIdx.x;
    if (e >= NE) return;
    atomicAdd(&cnt[graph[2 * e]], 1);
}

__global__ __launch_bounds__(1024) void csr_scan_kernel(const int* __restrict__ cnt,
    int* __restrict__ row_ptr, int* __restrict__ cursor)
{
    __shared__ int sd[1024];
    int tid = threadIdx.x;
    const int chunk = (NN + 1023) / 1024;
    int start = tid * chunk;
    int end = start + chunk; if (end > NN) end = NN;
    int sum = 0;
    for (int j = start; j < end; j++) sum += cnt[j];
    sd[tid] = sum;
    __syncthreads();
    for (int off = 1; off < 1024; off <<= 1) {
        int v = 0;
        if (tid >= off) v = sd[tid - off];
        __syncthreads();
        if (tid >= off) sd[tid] += v;
        __syncthreads();
    }
    int run = (tid == 0) ? 0 : sd[tid - 1];
    for (int j = start; j < end; j++) {
        row_ptr[j] = run;
        cursor[j]  = run;
        run += cnt[j];
    }
    if (tid == 0) row_ptr[NN] = NE;
}

__global__ __launch_bounds__(256) void csr_scatter_kernel(const int* __restrict__ graph,
    int* __restrict__ cursor, int* __restrict__ edge_list)
{
    int e = blockIdx.x * 256 + threadIdx.x;
    if (e >= NE) return;
    int p = atomicAdd(&cursor[graph[2 * e]], 1);
    edge_list[p] = e;
}

// Permuted edge streams in CSR order: rbf as bf16 MFMA-A rows (K=32 padded), cut/sense/dst.
// sin(k*base) via Chebyshev recurrence: s_{k+1} = 2cos(base)*s_k - s_{k-1} (1 sincos total).
__global__ __launch_bounds__(256) void edge_stream_kernel(
    const int* __restrict__ edge_list, const int* __restrict__ graph,
    const float* __restrict__ dist, const float* __restrict__ sense,
    u16* __restrict__ rbf_bf, float* __restrict__ cut_p,
    float* __restrict__ sense_p, int* __restrict__ dst_p)
{
    int j = blockIdx.x * 256 + threadIdx.x;
    if (j >= NE) return;
    int e = edge_list[j];
    float d = dist[e];
    float inv = 1.f / d;
    float base = PI_ * d / RC_;
    float s1, c1;
    __sincosf(base, &s1, &c1);
    float twoc = c1 + c1;
    u16* rb = rbf_bf + (size_t)j * 32;
    float sprev = 0.f, scur = s1;
    #pragma unroll
    for (int k = 0; k < RBFN; k++) {
        rb[k] = f2b(scur * inv);
        float snext = twoc * scur - sprev;
        sprev = scur; scur = snext;
    }
    #pragma unroll
    for (int k = RBFN; k < 32; k++) rb[k] = 0;
    cut_p[j] = 0.5f * (c1 + 1.f) * (d < RC_ ? 1.f : 0.f);
    dst_p[j] = graph[2 * e + 1];
    sense_p[3 * j + 0] = sense[3 * e + 0];
    sense_p[3 * j + 1] = sense[3 * e + 1];
    sense_p[3 * j + 2] = sense[3 * e + 2];
}

// ---------------------------------------------------------------- fused node MLP (iter-0 message path)
// Ob = (silu(A@W1^T + b1)) @ W2^T + b2.  A:(M,K1) bf16, W1:(128,K1), W2:(384,128).
// PACK layout (for edge gather): row of 384 u16 per node:
//   [0..255]  = (comp0, comp1) interleaved at f*2 + c   (c = gn>>7 for gn<256)
//   [256..383]= comp2 planar at 256 + (gn&127)
template<int K1, bool PACK>
__global__ __launch_bounds__(256) void mlp_kernel(const u16* __restrict__ A,
    const u16* __restrict__ W1, const float* __restrict__ b1,
    const u16* __restrict__ W2, const float* __restrict__ b2,
    u16* __restrict__ Ob, int M)
{
    __shared__ u16 As[64][KB + LPAD];
    __shared__ u16 Ws[128][KB + LPAD];
    __shared__ u16 T[64][KB + LPAD];
    const int bm = blockIdx.x * 64;
    const int tid = threadIdx.x;
    const int wave = tid >> 6, lane = tid & 63;
    const int wm  = (wave >> 1) * 32;
    const int wn1 = (wave & 1) * 64;
    const int wn  = (wave & 1) * 32;
    const int quad = lane >> 4, lr = lane & 15;
    const int r = tid >> 2, q = tid & 3;

    floatx4 acc1[2][4];
    #pragma unroll
    for (int i = 0; i < 2; i++)
        #pragma unroll
        for (int j = 0; j < 4; j++) acc1[i][j] = (floatx4)0.f;

    for (int ko = 0; ko < K1; ko += KB) {
        {
            int gm = bm + r;
            u16* dA = &As[r][q * 32];
            if (gm < M) {
                const u16* ap = A + (size_t)gm * K1 + ko + q * 32;
                #pragma unroll
                for (int x = 0; x < 32; x += 8)
                    *(bf16x8*)&dA[x] = *(const bf16x8*)(ap + x);
            } else {
                #pragma unroll
                for (int x = 0; x < 32; x += 8)
                    *(bf16x8*)&dA[x] = (bf16x8)0;
            }
            #pragma unroll
            for (int h = 0; h < 2; h++) {
                int wr = r + h * 64;
                const u16* wp = W1 + (size_t)wr * K1 + ko + q * 32;
                u16* dW = &Ws[wr][q * 32];
                #pragma unroll
                for (int x = 0; x < 32; x += 8)
                    *(bf16x8*)&dW[x] = *(const bf16x8*)(wp + x);
            }
        }
        __syncthreads();
        #pragma unroll
        for (int kk = 0; kk < KB; kk += 32) {
            bf16x8 a0 = *(const bf16x8*)&As[wm + lr     ][kk + quad * 8];
            bf16x8 a1 = *(const bf16x8*)&As[wm + 16 + lr][kk + quad * 8];
            #pragma unroll
            for (int j = 0; j < 4; j++) {
                bf16x8 b = *(const bf16x8*)&Ws[wn1 + j * 16 + lr][kk + quad * 8];
                acc1[0][j] = __builtin_amdgcn_mfma_f32_16x16x32_bf16(a0, b, acc1[0][j], 0, 0, 0);
                acc1[1][j] = __builtin_amdgcn_mfma_f32_16x16x32_bf16(a1, b, acc1[1][j], 0, 0, 0);
            }
        }
        __syncthreads();
    }
    #pragma unroll
    for (int i = 0; i < 2; i++) {
        #pragma unroll
        for (int j = 0; j < 4; j++) {
            int col = wn1 + j * 16 + lr;
            float bb = b1[col];
            #pragma unroll
            for (int rr = 0; rr < 4; rr++) {
                int row = wm + i * 16 + quad * 4 + rr;
                float v = acc1[i][j][rr] + bb;
                v = v / (1.f + __expf(-v));
                T[row][col] = f2b(v);
            }
        }
    }
    __syncthreads();

    for (int c0 = 0; c0 < F3; c0 += 64) {
        {
            const u16* wp = W2 + (size_t)(c0 + r) * KB + q * 32;
            u16* dW = &Ws[r][q * 32];
            #pragma unroll
            for (int x = 0; x < 32; x += 8)
                *(bf16x8*)&dW[x] = *(const bf16x8*)(wp + x);
        }
        __syncthreads();
        floatx4 acc2[2][2];
        #pragma unroll
        for (int i = 0; i < 2; i++)
            #pragma unroll
            for (int j = 0; j < 2; j++) acc2[i][j] = (floatx4)0.f;
        #pragma unroll
        for (int kk = 0; kk < KB; kk += 32) {
            bf16x8 a0 = *(const bf16x8*)&T[wm + lr     ][kk + quad * 8];
            bf16x8 a1 = *(const bf16x8*)&T[wm + 16 + lr][kk + quad * 8];
            bf16x8 b0 = *(const bf16x8*)&Ws[wn + lr     ][kk + quad * 8];
            bf16x8 b1 = *(const bf16x8*)&Ws[wn + 16 + lr][kk + quad * 8];
            acc2[0][0] = __builtin_amdgcn_mfma_f32_16x16x32_bf16(a0, b0, acc2[0][0], 0, 0, 0);
            acc2[0][1] = __builtin_amdgcn_mfma_f32_16x16x32_bf16(a0, b1, acc2[0][1], 0, 0, 0);
            acc2[1][0] = __builtin_amdgcn_mfma_f32_16x16x32_bf16(a1, b0, acc2[1][0], 0, 0, 0);
            acc2[1][1] = __builtin_amdgcn_mfma_f32_16x16x32_bf16(a1, b1, acc2[1][1], 0, 0, 0);
        }
        #pragma unroll
        for (int i = 0; i < 2; i++) {
            #pragma unroll
            for (int j = 0; j < 2; j++) {
                int gn = c0 + wn + j * 16 + lr;
                float bb = b2[gn];
                #pragma unroll
                for (int rr = 0; rr < 4; rr++) {
                    int gm = bm + wm + i * 16 + quad * 4 + rr;
                    if (gm < M) {
                        u16 val = f2b(acc2[i][j][rr] + bb);
                        if (PACK) {
                            int off = (gn < 256) ? ((gn & 127) * 2 + (gn >> 7))
                                                 : (256 + (gn & 127));
                            Ob[(size_t)gm * F3 + off] = val;
                        } else {
                            Ob[(size_t)gm * F3 + gn] = val;
                        }
                    }
                }
            }
        }
        __syncthreads();
    }
}

// Dual GEMM: U = A@Wu^T, V = A@Wv^T (K=128, Nc=128). bf16 outs.
__global__ __launch_bounds__(256) void gemm_uv(const u16* __restrict__ A,
    const u16* __restrict__ Wu, const u16* __restrict__ Wv,
    u16* __restrict__ U, u16* __restrict__ V, int M)
{
    __shared__ u16 As[64][KB + LPAD];
    __shared__ u16 Bu[64][KB + LPAD];
    __shared__ u16 Bv[64][KB + LPAD];
    const int bm = blockIdx.x * 64;
    const int bn = blockIdx.y * 64;
    const int tid = threadIdx.x;
    const int r = tid >> 2;
    const int q = tid & 3;
    const int wave = tid >> 6;
    const int lane = tid & 63;
    const int wm = (wave >> 1) * 32;
    const int wn = (wave & 1) * 32;
    const int quad = lane >> 4;
    const int lr = lane & 15;

    floatx4 au[2][2], av[2][2];
    #pragma unroll
    for (int i = 0; i < 2; i++)
        #pragma unroll
        for (int j = 0; j < 2; j++) { au[i][j] = (floatx4)0.f; av[i][j] = (floatx4)0.f; }

    {
        int gm = bm + r;
        u16* dA = &As[r][q * 32];
        if (gm < M) {
            const u16* ap = A + (size_t)gm * KB + q * 32;
            #pragma unroll
            for (int x = 0; x < 32; x += 8)
                *(bf16x8*)&dA[x] = *(const bf16x8*)(ap + x);
        } else {
            #pragma unroll
            for (int x = 0; x < 32; x += 8)
                *(bf16x8*)&dA[x] = (bf16x8)0;
        }
        int gn = bn + r;
        const u16* up = Wu + (size_t)gn * KB + q * 32;
        const u16* vp = Wv + (size_t)gn * KB + q * 32;
        u16* dU = &Bu[r][q * 32];
        u16* dV = &Bv[r][q * 32];
        #pragma unroll
        for (int x = 0; x < 32; x += 8) {
            *(bf16x8*)&dU[x] = *(const bf16x8*)(up + x);
            *(bf16x8*)&dV[x] = *(const bf16x8*)(vp + x);
        }
    }
    __syncthreads();
    #pragma unroll
    for (int kk = 0; kk < KB; kk += 32) {
        bf16x8 a0 = *(const bf16x8*)&As[wm + lr     ][kk + quad * 8];
        bf16x8 a1 = *(const bf16x8*)&As[wm + 16 + lr][kk + quad * 8];
        bf16x8 u0 = *(const bf16x8*)&Bu[wn + lr     ][kk + quad * 8];
        bf16x8 u1 = *(const bf16x8*)&Bu[wn + 16 + lr][kk + quad * 8];
        bf16x8 v0 = *(const bf16x8*)&Bv[wn + lr     ][kk + quad * 8];
        bf16x8 v1 = *(const bf16x8*)&Bv[wn + 16 + lr][kk + quad * 8];
        au[0][0] = __builtin_amdgcn_mfma_f32_16x16x32_bf16(a0, u0, au[0][0], 0, 0, 0);
        au[0][1] = __builtin_amdgcn_mfma_f32_16x16x32_bf16(a0, u1, au[0][1], 0, 0, 0);
        au[1][0] = __builtin_amdgcn_mfma_f32_16x16x32_bf16(a1, u0, au[1][0], 0, 0, 0);
        au[1][1] = __builtin_amdgcn_mfma_f32_16x16x32_bf16(a1, u1, au[1][1], 0, 0, 0);
        av[0][0] = __builtin_amdgcn_mfma_f32_16x16x32_bf16(a0, v0, av[0][0], 0, 0, 0);
        av[0][1] = __builtin_amdgcn_mfma_f32_16x16x32_bf16(a0, v1, av[0][1], 0, 0, 0);
        av[1][0] = __builtin_amdgcn_mfma_f32_16x16x32_bf16(a1, v0, av[1][0], 0, 0, 0);
        av[1][1] = __builtin_amdgcn_mfma_f32_16x16x32_bf16(a1, v1, av[1][1], 0, 0, 0);
    }
    #pragma unroll
    for (int i = 0; i < 2; i++) {
        #pragma unroll
        for (int j = 0; j < 2; j++) {
            int gn = bn + wn + j * 16 + lr;
            #pragma unroll
            for (int rr = 0; rr < 4; rr++) {
                int gm = bm + wm + i * 16 + quad * 4 + rr;
                if (gm < M) {
                    U[(size_t)gm * FD + gn] = f2b(au[i][j][rr]);
                    V[(size_t)gm * FD + gn] = f2b(av[i][j][rr]);
                }
            }
        }
    }
}

// ---------------------------------------------------------------- edge aggregate (MFMA dist_rep)
// 256 threads/node — PROVEN 138µs form, do not modify. Per 16-edge tile: dist_rep via 24
// MFMAs -> planar bf16 sdrep in LDS; gathers via packed (pair + planar) bf16 rows;
// serial runtime-bound nh loop (unroll / pair-gather / 512-thread variants all measured slower).
__global__ __launch_bounds__(256) void edge_mfma_kernel(
    const u16* __restrict__ rbf_bf, const float* __restrict__ cut_p,
    const float* __restrict__ sense_p, const int* __restrict__ dst_p,
    const u16* __restrict__ ewb, const float* __restrict__ eb,
    const u16* __restrict__ a_pk, const float* __restrict__ s_in,
    const float* __restrict__ v_in, const u16* __restrict__ v_pk,
    const int* __restrict__ row_ptr,
    float* __restrict__ s_out, u16* __restrict__ s_obf,
    float* __restrict__ v_out, u16* __restrict__ v_obf)
{
    __shared__ u16   sdrep[16 * SDS];   // planar bf16: [e][col] — 12.25 KB
    __shared__ float scut[16];
    __shared__ float ssen[16][4];
    __shared__ int   sdst[16];
    __shared__ float red[4 * 128];

    const int n = blockIdx.x;
    const int tid = threadIdx.x;
    const int wave = tid >> 6;
    const int lane = tid & 63;
    const int quad = lane >> 4;
    const int lr = lane & 15;
    const int f = tid & 127;
    const int half = tid >> 7;

    int beg = row_ptr[n], end = row_ptr[n + 1];
    float accs = 0.f, accv0 = 0.f, accv1 = 0.f, accv2 = 0.f;

    for (int t0 = beg; t0 < end; t0 += 16) {
        int cnt = end - t0; if (cnt > 16) cnt = 16;
        __syncthreads();   // previous tile fully consumed
        if (tid < 16) {
            scut[tid] = (tid < cnt) ? cut_p[t0 + tid] : 0.f;
            sdst[tid] = (tid < cnt) ? dst_p[t0 + tid] : 0;
        }
        if (tid >= 64 && tid < 64 + 3 * cnt) {
            int x = tid - 64;
            ssen[x / 3][x % 3] = sense_p[3 * t0 + x];
        }
        // MFMA: A = rbf rows (lane m=lr = edge), B = ew rows (6 col-tiles/wave)
        bf16x8 afrag;
        int ge = t0 + lr;
        if (ge < end) afrag = *(const bf16x8*)&rbf_bf[(size_t)ge * 32 + quad * 8];
        else          afrag = (bf16x8)0;
        floatx4 dacc[6];
        #pragma unroll
        for (int nt = 0; nt < 6; nt++) {
            int nrow = (wave * 6 + nt) * 16 + lr;
            bf16x8 bfrag = *(const bf16x8*)&ewb[(size_t)nrow * 32 + quad * 8];
            dacc[nt] = __builtin_amdgcn_mfma_f32_16x16x32_bf16(afrag, bfrag, (floatx4)0.f, 0, 0, 0);
        }
        __syncthreads();   // staged scalars visible
        // epilogue: (d + eb) * cut -> planar bf16 sdrep; C/D layout col=lr, row(edge)=quad*4+rr
        #pragma unroll
        for (int nt = 0; nt < 6; nt++) {
            int ncol = (wave * 6 + nt) * 16 + lr;
            float ebn = eb[ncol];
            #pragma unroll
            for (int rr = 0; rr < 4; rr++) {
                int e = quad * 4 + rr;
                sdrep[e * SDS + ncol] = f2b((dacc[nt][rr] + ebn) * scut[e]);
            }
        }
        __syncthreads();   // sdrep ready
        // aggregation: half h handles up to 8 edges
        int nh = cnt - half * 8; if (nh > 8) nh = 8;
        for (int k = 0; k < nh; k++) {
            int e = half * 8 + k;
            int dst = sdst[e];
            const u16* sr = &sdrep[e * SDS];
            float drv = b2f(sr[f]);
            float drs = b2f(sr[FD + f]);
            float drd = b2f(sr[2 * FD + f]);
            const u16* ar = a_pk + (size_t)dst * F3;
            u32 ap = *(const u32*)(ar + f * 2);
            float rv = b2f((u16)(ap & 0xffff)) * drv;
            float rs = b2f((u16)(ap >> 16))    * drs;
            float rd = b2f(ar[256 + f])        * drd;
            accs += rs;
            const u16* vr = v_pk + (size_t)dst * F3;
            u32 vp = *(const u32*)(vr + f * 2);
            accv0 += b2f((u16)(vp & 0xffff)) * rv + ssen[e][0] * rd;
            accv1 += b2f((u16)(vp >> 16))    * rv + ssen[e][1] * rd;
            accv2 += b2f(vr[256 + f])        * rv + ssen[e][2] * rd;
        }
    }
    // combine halves, write
    __syncthreads();
    if (half == 1) {
        red[f] = accs; red[128 + f] = accv0; red[256 + f] = accv1; red[384 + f] = accv2;
    }
    __syncthreads();
    if (half == 0) {
        accs  += red[f];       accv0 += red[128 + f];
        accv1 += red[256 + f]; accv2 += red[384 + f];
        int nb = n * FD + f;
        float so = s_in[nb] + 2.f * accs;
        s_out[nb] = so; s_obf[nb] = f2b(so);
        int vb = n * F3 + f;
        float w0 = v_in[vb]           + 2.f * accv0;
        float w1 = v_in[vb + FD]      + 2.f * accv1;
        float w2 = v_in[vb + 2 * FD]  + 2.f * accv2;
        v_out[vb]          = w0; v_obf[vb]          = f2b(w0);
        v_out[vb + FD]     = w1; v_obf[vb + FD]     = f2b(w1);
        v_out[vb + 2 * FD] = w2; v_obf[vb + 2 * FD] = f2b(w2);
    }
}

// ---------------------------------------------------------------- fused mlp2 + build_h + update + NEXT
// a2 = (silu(h@aw1^T+ab1))@aw2^T+ab2 with h = [s_mid, |Vv|] built in A-staging (no h_bf).
// GEMM2 chunks reordered (avv,asv,ass per f-half); ass chunk performs the node update inline
// AND deposits the fresh s (bf16) into the dead As LDS buffer.  Then:
//   LAST=false: appended mlp1 of the NEXT iteration (A = As, out = a_pk, PACK) — no launch, no HBM A-read.
//   LAST=true : appended final head (GEMM ow1 + silu + ow2-dot -> nodeval), f32 T aliased onto Ws.
template<bool LAST>
__global__ __launch_bounds__(256) void mlp2_update_next_kernel(
    const u16* __restrict__ sbf_mid, const float* __restrict__ s_mid,
    const float* __restrict__ v_mid,
    const u16* __restrict__ Uv, const u16* __restrict__ Vv,
    const u16* __restrict__ W1, const float* __restrict__ b1,
    const u16* __restrict__ W2, const float* __restrict__ b2,
    float* __restrict__ s_out,
    float* __restrict__ v_out, u16* __restrict__ v_pk,
    const u16* __restrict__ N_W1, const float* __restrict__ N_b1,
    const u16* __restrict__ N_W2, const float* __restrict__ N_b2,
    u16* __restrict__ a_pk,
    const u16* __restrict__ H_W1, const float* __restrict__ H_b1,
    const float* __restrict__ ow2, const float* __restrict__ ob2,
    float* __restrict__ nodeval, int M)
{
    __shared__ u16 As[64][KB + LPAD];
    __shared__ u16 Ws[128][KB + LPAD];
    __shared__ u16 T[64][KB + LPAD];
    const int bm = blockIdx.x * 64;
    const int tid = threadIdx.x;
    const int wave = tid >> 6, lane = tid & 63;
    const int wm  = (wave >> 1) * 32;
    const int wn1 = (wave & 1) * 64;
    const int wn  = (wave & 1) * 32;
    const int quad = lane >> 4, lr = lane & 15;
    const int r = tid >> 2, q = tid & 3;

    floatx4 acc1[2][4];
    #pragma unroll
    for (int i = 0; i < 2; i++)
        #pragma unroll
        for (int j = 0; j < 4; j++) acc1[i][j] = (floatx4)0.f;

    // ---- GEMM1, ko chunk 0: A cols = s_mid bf16
    {
        int gm = bm + r;
        u16* dA = &As[r][q * 32];
        if (gm < M) {
            const u16* ap = sbf_mid + (size_t)gm * FD + q * 32;
            #pragma unroll
            for (int x = 0; x < 32; x += 8)
                *(bf16x8*)&dA[x] = *(const bf16x8*)(ap + x);
        } else {
            #pragma unroll
            for (int x = 0; x < 32; x += 8)
                *(bf16x8*)&dA[x] = (bf16x8)0;
        }
        #pragma unroll
        for (int h = 0; h < 2; h++) {
            int wr = r + h * 64;
            const u16* wp = W1 + (size_t)wr * F2 + q * 32;
            u16* dW = &Ws[wr][q * 32];
            #pragma unroll
            for (int x = 0; x < 32; x += 8)
                *(bf16x8*)&dW[x] = *(const bf16x8*)(wp + x);
        }
    }
    __syncthreads();
    #pragma unroll
    for (int kk = 0; kk < KB; kk += 32) {
        bf16x8 a0 = *(const bf16x8*)&As[wm + lr     ][kk + quad * 8];
        bf16x8 a1 = *(const bf16x8*)&As[wm + 16 + lr][kk + quad * 8];
        #pragma unroll
        for (int j = 0; j < 4; j++) {
            bf16x8 b = *(const bf16x8*)&Ws[wn1 + j * 16 + lr][kk + quad * 8];
            acc1[0][j] = __builtin_amdgcn_mfma_f32_16x16x32_bf16(a0, b, acc1[0][j], 0, 0, 0);
            acc1[1][j] = __builtin_amdgcn_mfma_f32_16x16x32_bf16(a1, b, acc1[1][j], 0, 0, 0);
        }
    }
    __syncthreads();
    // ---- GEMM1, ko chunk 1: A cols = |Vv| computed inline (build_h fused)
    {
        int gm = bm + r;
        u16* dA = &As[r][q * 32];
        if (gm < M) {
            const u16* vvp = Vv + (size_t)gm * F3 + q * 32;
            bf16x8 c0[4], c1[4], c2[4];
            #pragma unroll
            for (int t = 0; t < 4; t++) {
                c0[t] = *(const bf16x8*)(vvp + t * 8);
                c1[t] = *(const bf16x8*)(vvp + FD + t * 8);
                c2[t] = *(const bf16x8*)(vvp + 2 * FD + t * 8);
            }
            #pragma unroll
            for (int t = 0; t < 4; t++) {
                #pragma unroll
                for (int x = 0; x < 8; x++) {
                    float a = b2f((u16)c0[t][x]);
                    float b = b2f((u16)c1[t][x]);
                    float c = b2f((u16)c2[t][x]);
                    dA[t * 8 + x] = f2b(sqrtf(a * a + b * b + c * c));
                }
            }
        } else {
            #pragma unroll
            for (int x = 0; x < 32; x += 8)
                *(bf16x8*)&dA[x] = (bf16x8)0;
        }
        #pragma unroll
        for (int h = 0; h < 2; h++) {
            int wr = r + h * 64;
            const u16* wp = W1 + (size_t)wr * F2 + KB + q * 32;
            u16* dW = &Ws[wr][q * 32];
            #pragma unroll
            for (int x = 0; x < 32; x += 8)
                *(bf16x8*)&dW[x] = *(const bf16x8*)(wp + x);
        }
    }
    __syncthreads();
    #pragma unroll
    for (int kk = 0; kk < KB; kk += 32) {
        bf16x8 a0 = *(const bf16x8*)&As[wm + lr     ][kk + quad * 8];
        bf16x8 a1 = *(const bf16x8*)&As[wm + 16 + lr][kk + quad * 8];
        #pragma unroll
        for (int j = 0; j < 4; j++) {
            bf16x8 b = *(const bf16x8*)&Ws[wn1 + j * 16 + lr][kk + quad * 8];
            acc1[0][j] = __builtin_amdgcn_mfma_f32_16x16x32_bf16(a0, b, acc1[0][j], 0, 0, 0);
            acc1[1][j] = __builtin_amdgcn_mfma_f32_16x16x32_bf16(a1, b, acc1[1][j], 0, 0, 0);
        }
    }
    __syncthreads();
    // T = silu(acc1 + b1) as bf16
    #pragma unroll
    for (int i = 0; i < 2; i++) {
        #pragma unroll
        for (int j = 0; j < 4; j++) {
            int col = wn1 + j * 16 + lr;
            float bb = b1[col];
            #pragma unroll
            for (int rr = 0; rr < 4; rr++) {
                int row = wm + i * 16 + quad * 4 + rr;
                float v = acc1[i][j][rr] + bb;
                v = v / (1.f + __expf(-v));
                T[row][col] = f2b(v);
            }
        }
    }
    __syncthreads();

    // ---- GEMM2: chunk order (avv, asv, ass) per f-half; update fused into ass epilogue;
    //      fresh s (bf16) deposited into As for the appended NEXT phase.
    float avvr[2][2][4], asvr[2][2][4];
    #pragma unroll
    for (int part = 0; part < 2; part++) {
        #pragma unroll
        for (int piece = 0; piece < 3; piece++) {
            const int c0 = piece * 128 + part * 64;
            {
                const u16* wp = W2 + (size_t)(c0 + r) * KB + q * 32;
                u16* dW = &Ws[r][q * 32];
                #pragma unroll
                for (int x = 0; x < 32; x += 8)
                    *(bf16x8*)&dW[x] = *(const bf16x8*)(wp + x);
            }
            __syncthreads();
            floatx4 acc2[2][2];
            #pragma unroll
            for (int i = 0; i < 2; i++)
                #pragma unroll
                for (int j = 0; j < 2; j++) acc2[i][j] = (floatx4)0.f;
            #pragma unroll
            for (int kk = 0; kk < KB; kk += 32) {
                bf16x8 a0 = *(const bf16x8*)&T[wm + lr     ][kk + quad * 8];
                bf16x8 a1 = *(const bf16x8*)&T[wm + 16 + lr][kk + quad * 8];
                bf16x8 b0 = *(const bf16x8*)&Ws[wn + lr     ][kk + quad * 8];
                bf16x8 b1 = *(const bf16x8*)&Ws[wn + 16 + lr][kk + quad * 8];
                acc2[0][0] = __builtin_amdgcn_mfma_f32_16x16x32_bf16(a0, b0, acc2[0][0], 0, 0, 0);
                acc2[0][1] = __builtin_amdgcn_mfma_f32_16x16x32_bf16(a0, b1, acc2[0][1], 0, 0, 0);
                acc2[1][0] = __builtin_amdgcn_mfma_f32_16x16x32_bf16(a1, b0, acc2[1][0], 0, 0, 0);
                acc2[1][1] = __builtin_amdgcn_mfma_f32_16x16x32_bf16(a1, b1, acc2[1][1], 0, 0, 0);
            }
            if (piece == 0) {
                #pragma unroll
                for (int i = 0; i < 2; i++)
                    #pragma unroll
                    for (int j = 0; j < 2; j++) {
                        int gn = c0 + wn + j * 16 + lr;
                        float bb = b2[gn];
                        #pragma unroll
                        for (int rr = 0; rr < 4; rr++)
                            avvr[i][j][rr] = acc2[i][j][rr] + bb;
                    }
            } else if (piece == 1) {
                #pragma unroll
                for (int i = 0; i < 2; i++)
                    #pragma unroll
                    for (int j = 0; j < 2; j++) {
                        int gn = c0 + wn + j * 16 + lr;
                        float bb = b2[gn];
                        #pragma unroll
                        for (int rr = 0; rr < 4; rr++)
                            asvr[i][j][rr] = acc2[i][j][rr] + bb;
                    }
            } else {
                // ass chunk: full node update + As s-deposit
                #pragma unroll
                for (int i = 0; i < 2; i++) {
                    #pragma unroll
                    for (int j = 0; j < 2; j++) {
                        int gn = c0 + wn + j * 16 + lr;
                        int f  = gn - 256;          // = part*64 + wn + j*16 + lr
                        float bb = b2[gn];
                        #pragma unroll
                        for (int rr = 0; rr < 4; rr++) {
                            int row = wm + i * 16 + quad * 4 + rr;
                            int gm = bm + row;
                            if (gm < M) {
                                float ass = acc2[i][j][rr] + bb;
                                float asv = asvr[i][j][rr];
                                float avv = avvr[i][j][rr];
                                int vb = gm * F3 + f;
                                float u0 = b2f(Uv[vb]);
                                float u1 = b2f(Uv[vb + FD]);
                                float u2 = b2f(Uv[vb + 2 * FD]);
                                float w0 = b2f(Vv[vb]);
                                float w1 = b2f(Vv[vb + FD]);
                                float w2 = b2f(Vv[vb + 2 * FD]);
                                float dot = u0 * w0 + u1 * w1 + u2 * w2;
                                int nb = gm * FD + f;
                                float so = s_mid[nb] + ass + asv * dot;
                                s_out[nb] = so;
                                As[row][f] = f2b(so);
                                float y0 = v_mid[vb]          + avv * u0;
                                float y1 = v_mid[vb + FD]     + avv * u1;
                                float y2 = v_mid[vb + 2 * FD] + avv * u2;
                                v_out[vb]          = y0;
                                v_out[vb + FD]     = y1;
                                v_out[vb + 2 * FD] = y2;
                                char* vpb = (char*)v_pk + (size_t)gm * (2 * F3);
                                *(u32*)(vpb + 4 * f) = pack2(y0, y1);
                                *(u16*)(vpb + 512 + 2 * f) = f2b(y2);
                            } else {
                                As[row][f] = 0;
                            }
                        }
                    }
                }
            }
            __syncthreads();
        }
    }
    // As now holds this block's fresh s (bf16), all 64 rows x 128 cols.

    if constexpr (!LAST) {
        // ---------------- appended mlp1 of next iteration (A = As, K=128)
        {
            #pragma unroll
            for (int h = 0; h < 2; h++) {
                int wr = r + h * 64;
                const u16* wp = N_W1 + (size_t)wr * KB + q * 32;
                u16* dW = &Ws[wr][q * 32];
                #pragma unroll
                for (int x = 0; x < 32; x += 8)
                    *(bf16x8*)&dW[x] = *(const bf16x8*)(wp + x);
            }
        }
        __syncthreads();
        #pragma unroll
        for (int i = 0; i < 2; i++)
            #pragma unroll
            for (int j = 0; j < 4; j++) acc1[i][j] = (floatx4)0.f;
        #pragma unroll
        for (int kk = 0; kk < KB; kk += 32) {
            bf16x8 a0 = *(const bf16x8*)&As[wm + lr     ][kk + quad * 8];
            bf16x8 a1 = *(const bf16x8*)&As[wm + 16 + lr][kk + quad * 8];
            #pragma unroll
            for (int j = 0; j < 4; j++) {
                bf16x8 b = *(const bf16x8*)&Ws[wn1 + j * 16 + lr][kk + quad * 8];
                acc1[0][j] = __builtin_amdgcn_mfma_f32_16x16x32_bf16(a0, b, acc1[0][j], 0, 0, 0);
                acc1[1][j] = __builtin_amdgcn_mfma_f32_16x16x32_bf16(a1, b, acc1[1][j], 0, 0, 0);
            }
        }
        __syncthreads();
        #pragma unroll
        for (int i = 0; i < 2; i++) {
            #pragma unroll
            for (int j = 0; j < 4; j++) {
                int col = wn1 + j * 16 + lr;
                float bb = N_b1[col];
                #pragma unroll
                for (int rr = 0; rr < 4; rr++) {
                    int row = wm + i * 16 + quad * 4 + rr;
                    float v = acc1[i][j][rr] + bb;
                    v = v / (1.f + __expf(-v));
                    T[row][col] = f2b(v);
                }
            }
        }
        __syncthreads();
        for (int c0 = 0; c0 < F3; c0 += 64) {
            {
                const u16* wp = N_W2 + (size_t)(c0 + r) * KB + q * 32;
                u16* dW = &Ws[r][q * 32];
                #pragma unroll
                for (int x = 0; x < 32; x += 8)
                    *(bf16x8*)&dW[x] = *(const bf16x8*)(wp + x);
            }
            __syncthreads();
            floatx4 acc2[2][2];
            #pragma unroll
            for (int i = 0; i < 2; i++)
                #pragma unroll
                for (int j = 0; j < 2; j++) acc2[i][j] = (floatx4)0.f;
            #pragma unroll
            for (int kk = 0; kk < KB; kk += 32) {
                bf16x8 a0 = *(const bf16x8*)&T[wm + lr     ][kk + quad * 8];
                bf16x8 a1 = *(const bf16x8*)&T[wm + 16 + lr][kk + quad * 8];
                bf16x8 b0 = *(const bf16x8*)&Ws[wn + lr     ][kk + quad * 8];
                bf16x8 b1 = *(const bf16x8*)&Ws[wn + 16 + lr][kk + quad * 8];
                acc2[0][0] = __builtin_amdgcn_mfma_f32_16x16x32_bf16(a0, b0, acc2[0][0], 0, 0, 0);
                acc2[0][1] = __builtin_amdgcn_mfma_f32_16x16x32_bf16(a0, b1, acc2[0][1], 0, 0, 0);
                acc2[1][0] = __builtin_amdgcn_mfma_f32_16x16x32_bf16(a1, b0, acc2[1][0], 0, 0, 0);
                acc2[1][1] = __builtin_amdgcn_mfma_f32_16x16x32_bf16(a1, b1, acc2[1][1], 0, 0, 0);
            }
            #pragma unroll
            for (int i = 0; i < 2; i++) {
                #pragma unroll
                for (int j = 0; j < 2; j++) {
                    int gn = c0 + wn + j * 16 + lr;
                    float bb = N_b2[gn];
                    #pragma unroll
                    for (int rr = 0; rr < 4; rr++) {
                        int gm = bm + wm + i * 16 + quad * 4 + rr;
                        if (gm < M) {
                            u16 val = f2b(acc2[i][j][rr] + bb);
                            int off = (gn < 256) ? ((gn & 127) * 2 + (gn >> 7))
                                                 : (256 + (gn & 127));
                            a_pk[(size_t)gm * F3 + off] = val;
                        }
                    }
                }
            }
            __syncthreads();
        }
    } else {
        // ---------------- appended final head: t = silu(s@ow1^T+ob1); nodeval = t·ow2 + ob2
        {
            #pragma unroll
            for (int h = 0; h < 2; h++) {
                int wr = r + h * 64;
                const u16* wp = H_W1 + (size_t)wr * KB + q * 32;
                u16* dW = &Ws[wr][q * 32];
                #pragma unroll
                for (int x = 0; x < 32; x += 8)
                    *(bf16x8*)&dW[x] = *(const bf16x8*)(wp + x);
            }
        }
        __syncthreads();
        #pragma unroll
        for (int i = 0; i < 2; i++)
            #pragma unroll
            for (int j = 0; j < 4; j++) acc1[i][j] = (floatx4)0.f;
        #pragma unroll
        for (int kk = 0; kk < KB; kk += 32) {
            bf16x8 a0 = *(const bf16x8*)&As[wm + lr     ][kk + quad * 8];
            bf16x8 a1 = *(const bf16x8*)&As[wm + 16 + lr][kk + quad * 8];
            #pragma unroll
            for (int j = 0; j < 4; j++) {
                bf16x8 b = *(const bf16x8*)&Ws[wn1 + j * 16 + lr][kk + quad * 8];
                acc1[0][j] = __builtin_amdgcn_mfma_f32_16x16x32_bf16(a0, b, acc1[0][j], 0, 0, 0);
                acc1[1][j] = __builtin_amdgcn_mfma_f32_16x16x32_bf16(a1, b, acc1[1][j], 0, 0, 0);
            }
        }
        __syncthreads();   // Ws fully consumed; As fully consumed
        float* Tf   = (float*)&Ws[0][0];   // 64 x 132 f32 = 33792 B <= 34816 B
        float* ow2s = (float*)&As[0][0];   // 128 f32 = 512 B
        if (tid < KB) ow2s[tid] = ow2[tid];
        #pragma unroll
        for (int i = 0; i < 2; i++) {
            #pragma unroll
            for (int j = 0; j < 4; j++) {
                int col = wn1 + j * 16 + lr;
                float bb = H_b1[col];
                #pragma unroll
                for (int rr = 0; rr < 4; rr++) {
                    int row = wm + i * 16 + quad * 4 + rr;
                    float v = acc1[i][j][rr] + bb;
                    v = v / (1.f + __expf(-v));
                    Tf[row * 132 + col] = v;
                }
            }
        }
        __syncthreads();
        int nl = tid >> 2, seg = tid & 3;
        float v = 0.f;
        #pragma unroll
        for (int x = 0; x < 32; x++) {
            int col = seg * 32 + x;
            v += Tf[nl * 132 + col] * ow2s[col];
        }
        v += __shfl_down(v, 2);
        v += __shfl_down(v, 1);
        if (seg == 0) {
            int gm = bm + nl;
            if (gm < M) nodeval[gm] = v + ob2[0];
        }
    }
}

__global__ __launch_bounds__(1024) void mol_reduce_kernel(const float* __restrict__ nodeval,
    const int* __restrict__ gidx, float* __restrict__ out)
{
    __shared__ float mol[NMOL];
    int tid = threadIdx.x;
    if (tid < NMOL) mol[tid] = 0.f;
    __syncthreads();
    int cur = -1; float acc = 0.f;
    for (int x = tid; x < NN; x += 1024) {
        int g = gidx[x];
        float v = nodeval[x];
        if (g != cur) {
            if (cur >= 0) atomicAdd(&mol[cur], acc);
            cur = g; acc = v;
        } else acc += v;
    }
    if (cur >= 0) atomicAdd(&mol[cur], acc);
    __syncthreads();
    if (tid < NMOL) out[tid] = mol[tid];
}

// ---------------------------------------------------------------- launch
extern "C" void kernel_launch(void* const* d_in, const int* in_sizes, int n_in,
                              void* d_out, int out_size, void* d_ws, size_t ws_size,
                              hipStream_t stream)
{
    const int*   z     = (const int*)d_in[0];
    const int*   graph = (const int*)d_in[1];
    const float* dist  = (const float*)d_in[2];
    const float* sense = (const float*)d_in[3];
    const int*   gidx  = (const int*)d_in[4];
    const float* emb   = (const float*)d_in[5];
    const float* mw1   = (const float*)d_in[6];
    const float* mb1   = (const float*)d_in[7];
    const float* mw2   = (const float*)d_in[8];
    const float* mb2   = (const float*)d_in[9];
    const float* ew    = (const float*)d_in[10];
    const float* eb    = (const float*)d_in[11];
    const float* uw    = (const float*)d_in[12];
    const float* vw    = (const float*)d_in[13];
    const float* aw1   = (const float*)d_in[14];
    const float* ab1   = (const float*)d_in[15];
    const float* aw2   = (const float*)d_in[16];
    const float* ab2   = (const float*)d_in[17];
    const float* ow1   = (const float*)d_in[18];
    const float* ob1   = (const float*)d_in[19];
    const float* ow2   = (const float*)d_in[20];
    const float* ob2   = (const float*)d_in[21];
    float* out = (float*)d_out;

    // ---- workspace carve-up ----
    float* W = (float*)d_ws;
    float* s_a    = W; W += (size_t)NN * FD;
    float* s_b    = W; W += (size_t)NN * FD;
    float* v_a    = W; W += (size_t)NN * F3;
    float* v_b    = W; W += (size_t)NN * F3;
    float* cut_p  = W; W += (size_t)NE;
    float* sns_p  = W; W += (size_t)NE * 3;
    float* nodeval= W; W += (size_t)NN;
    u16* U = (u16*)W;
    u16* sbf_a = U; U += (size_t)NN * FD;
    u16* sbf_b = U; U += (size_t)NN * FD;
    u16* vbf_b = U; U += (size_t)NN * F3;
    u16* a_pk  = U; U += (size_t)NN * F3;
    u16* v_pk  = U; U += (size_t)NN * F3;
    u16* h_bf  = U; U += (size_t)NN * F2;   // unused (kept for layout stability)
    u16* a2_bf = U; U += (size_t)NN * F3;   // unused (kept for layout stability)
    u16* Uv_bf = U; U += (size_t)NN * F3;
    u16* Vv_bf = U; U += (size_t)NN * F3;
    u16* rbf_bf= U; U += (size_t)NE * 32;
    u16* ewb   = U; U += (size_t)NITER * F3 * 32;
    u16* wb    = U; U += 557056;
    int* ip = (int*)U;
    int* row_ptr   = ip; ip += NN + 1;
    int* cnt       = ip; ip += NN;
    int* cursor    = ip; ip += NN;
    int* edge_list = ip; ip += NE;
    int* dst_p     = ip; ip += NE;

    // bf16 weight table offsets
    u16* wb_mw1 = wb;            // 3*128*128
    u16* wb_mw2 = wb + 49152;    // 3*384*128
    u16* wb_uw  = wb + 196608;   // 3*128*128
    u16* wb_vw  = wb + 245760;   // 3*128*128
    u16* wb_aw1 = wb + 294912;   // 3*128*256
    u16* wb_aw2 = wb + 393216;   // 3*384*128
    u16* wb_ow1 = wb + 540672;   // 128*128

    const int TB = 256;
    dim3 b256(TB);

    // --- precompute (fused init covers: weight cvt, ew cvt, embed, v/v_pk/cnt zero) ---
    init_all_kernel<<<dim3((NN * F3 + TB - 1) / TB), b256, 0, stream>>>(
        mw1, 49152, mw2, 147456, uw, 49152, vw, 49152, aw1, 98304, aw2, 147456,
        ow1, 16384, wb, ew, ewb, z, emb, s_a, sbf_a, v_a, (int*)v_pk, cnt);
    csr_count_kernel<<<dim3((NE + TB - 1) / TB), b256, 0, stream>>>(graph, cnt);
    csr_scan_kernel<<<dim3(1), dim3(1024), 0, stream>>>(cnt, row_ptr, cursor);
    csr_scatter_kernel<<<dim3((NE + TB - 1) / TB), b256, 0, stream>>>(graph, cursor, edge_list);
    edge_stream_kernel<<<dim3((NE + TB - 1) / TB), b256, 0, stream>>>(
        edge_list, graph, dist, sense, rbf_bf, cut_p, sns_p, dst_p);

    dim3 gM((NN + 63) / 64);                   // fused MLPs / head
    dim3 gV2((3 * NN + 63) / 64, FD / 64);     // M=3N, Nc=128

    // iter-0 message MLP (later iterations' mlp1 are fused into mlp2_update_next)
    mlp_kernel<128, true><<<gM, b256, 0, stream>>>(sbf_a,
        wb_mw1, mb1, wb_mw2, mb2, a_pk, NN);

    for (int i = 0; i < NITER; i++) {
        edge_mfma_kernel<<<dim3(NN), b256, 0, stream>>>(
            rbf_bf, cut_p, sns_p, dst_p,
            ewb + (size_t)i * F3 * 32, eb + (size_t)i * F3,
            a_pk, s_a, v_a, v_pk, row_ptr, s_b, sbf_b, v_b, vbf_b);
        gemm_uv<<<gV2, b256, 0, stream>>>(vbf_b, wb_uw + (size_t)i * FD * FD,
            wb_vw + (size_t)i * FD * FD, Uv_bf, Vv_bf, 3 * NN);
        if (i < NITER - 1) {
            mlp2_update_next_kernel<false><<<gM, b256, 0, stream>>>(
                sbf_b, s_b, v_b, Uv_bf, Vv_bf,
                wb_aw1 + (size_t)i * FD * F2, ab1 + (size_t)i * FD,
                wb_aw2 + (size_t)i * F3 * FD, ab2 + (size_t)i * F3,
                s_a, v_a, v_pk,
                wb_mw1 + (size_t)(i + 1) * FD * FD, mb1 + (size_t)(i + 1) * FD,
                wb_mw2 + (size_t)(i + 1) * F3 * FD, mb2 + (size_t)(i + 1) * F3, a_pk,
                nullptr, nullptr, nullptr, nullptr, nullptr, NN);
        } else {
            mlp2_update_next_kernel<true><<<gM, b256, 0, stream>>>(
                sbf_b, s_b, v_b, Uv_bf, Vv_bf,
                wb_aw1 + (size_t)i * FD * F2, ab1 + (size_t)i * FD,
                wb_aw2 + (size_t)i * F3 * FD, ab2 + (size_t)i * F3,
                s_a, v_a, v_pk,
                nullptr, nullptr, nullptr, nullptr, nullptr,
                wb_ow1, ob1, ow2, ob2, nodeval, NN);
        }
    }

    mol_reduce_kernel<<<dim3(1), dim3(1024), 0, stream>>>(nodeval, gidx, out);
}

// Round 7
// 864.645 us; speedup vs baseline: 1.1422x; 1.0045x over previous
//
#include <hip/hip_runtime.h>
#include <math.h>

// Problem constants
#define NN 20000
#define NE 320000
#define FD 128
#define RBFN 20
#define RC_ 5.0f
#define NITER 3
#define NMOL 64
#define F3 384
#define F2 256
#define PI_ 3.14159265358979323846f
#define KB 128
#define LPAD 8
#define SDS 392   // u16 stride per sdrep edge row (384 + 8 pad)

typedef __attribute__((ext_vector_type(8))) short  bf16x8;
typedef __attribute__((ext_vector_type(4))) float  floatx4;
typedef unsigned short u16;
typedef unsigned int   u32;

__device__ __forceinline__ u16 f2b(float x) {
    union { float f; unsigned int u; } v; v.f = x;
    unsigned int u = v.u;
    return (u16)((u + 0x7fffu + ((u >> 16) & 1u)) >> 16);   // RNE
}
__device__ __forceinline__ float b2f(u16 x) {
    union { unsigned int u; float f; } v; v.u = ((unsigned int)x) << 16;
    return v.f;
}
__device__ __forceinline__ float blo(u32 w) {
    union { unsigned int u; float f; } v; v.u = w << 16; return v.f;
}
__device__ __forceinline__ float bhi(u32 w) {
    union { unsigned int u; float f; } v; v.u = w & 0xffff0000u; return v.f;
}
__device__ __forceinline__ u32 pack2(float a, float b) {
    return (u32)f2b(a) | ((u32)f2b(b) << 16);
}

// ---------------------------------------------------------------- fused one-time init:
// weight cvt (7 tables) + ew cvt + embed + v/v_pk/cnt zeroing, all independent ranges.
__global__ __launch_bounds__(256) void init_all_kernel(
    const float* s0, int n0, const float* s1, int n1, const float* s2, int n2,
    const float* s3, int n3, const float* s4, int n4, const float* s5, int n5,
    const float* s6, int n6, u16* __restrict__ wdst,
    const float* __restrict__ ew, u16* __restrict__ ewb,
    const int* __restrict__ z, const float* __restrict__ emb,
    float* __restrict__ s, u16* __restrict__ sbf,
    float* __restrict__ v_a, int* __restrict__ v_pk_i, int* __restrict__ cnt)
{
    int idx = blockIdx.x * 256 + threadIdx.x;
    if (idx < NN * F3) v_a[idx] = 0.f;
    if (idx < NN * F3 / 2) v_pk_i[idx] = 0;
    if (idx < NN) cnt[idx] = 0;
    if (idx < NN * FD) {
        int n = idx >> 7, f = idx & 127;
        float v = emb[z[n] * FD + f];
        s[idx] = v; sbf[idx] = f2b(v);
    }
    if (idx < NITER * F3 * 32) {
        int k = idx & 31;
        int row = idx >> 5;
        ewb[idx] = (k < RBFN) ? f2b(ew[row * RBFN + k]) : (u16)0;
    }
    {
        int w = idx;
        u16* dst = wdst;
        if (w < n0) { dst[w] = f2b(s0[w]); return; } w -= n0; dst += n0;
        if (w < n1) { dst[w] = f2b(s1[w]); return; } w -= n1; dst += n1;
        if (w < n2) { dst[w] = f2b(s2[w]); return; } w -= n2; dst += n2;
        if (w < n3) { dst[w] = f2b(s3[w]); return; } w -= n3; dst += n3;
        if (w < n4) { dst[w] = f2b(s4[w]); return; } w -= n4; dst += n4;
        if (w < n5) { dst[w] = f2b(s5[w]); return; } w -= n5; dst += n5;
        if (w < n6) { dst[w] = f2b(s6[w]); }
    }
}

// ---------------------------------------------------------------- CSR build
__global__ __launch_bounds__(256) void csr_count_kernel(const int* __restrict__ graph,
    int* __restrict__ cnt)
{
    int e = blockIdx.x * 256 + threadIdx.x;
    if (e >= NE) return;
    atomicAdd(&cnt[graph[2 * e]], 1);
}

__global__ __launch_bounds__(1024) void csr_scan_kernel(const int* __restrict__ cnt,
    int* __restrict__ row_ptr, int* __restrict__ cursor)
{
    __shared__ int sd[1024];
    int tid = threadIdx.x;
    const int chunk = (NN + 1023) / 1024;
    int start = tid * chunk;
    int end = start + chunk; if (end > NN) end = NN;
    int sum = 0;
    for (int j = start; j < end; j++) sum += cnt[j];
    sd[tid] = sum;
    __syncthreads();
    for (int off = 1; off < 1024; off <<= 1) {
        int v = 0;
        if (tid >= off) v = sd[tid - off];
        __syncthreads();
        if (tid >= off) sd[tid] += v;
        __syncthreads();
    }
    int run = (tid == 0) ? 0 : sd[tid - 1];
    for (int j = start; j < end; j++) {
        row_ptr[j] = run;
        cursor[j]  = run;
        run += cnt[j];
    }
    if (tid == 0) row_ptr[NN] = NE;
}

__global__ __launch_bounds__(256) void csr_scatter_kernel(const int* __restrict__ graph,
    int* __restrict__ cursor, int* __restrict__ edge_list)
{
    int e = blockIdx.x * 256 + threadIdx.x;
    if (e >= NE) return;
    int p = atomicAdd(&cursor[graph[2 * e]], 1);
    edge_list[p] = e;
}

// Permuted edge streams in CSR order: rbf as bf16 MFMA-A rows (K=32 padded), cut/sense/dst.
// sin(k*base) via Chebyshev recurrence: s_{k+1} = 2cos(base)*s_k - s_{k-1} (1 sincos total).
__global__ __launch_bounds__(256) void edge_stream_kernel(
    const int* __restrict__ edge_list, const int* __restrict__ graph,
    const float* __restrict__ dist, const float* __restrict__ sense,
    u16* __restrict__ rbf_bf, float* __restrict__ cut_p,
    float* __restrict__ sense_p, int* __restrict__ dst_p)
{
    int j = blockIdx.x * 256 + threadIdx.x;
    if (j >= NE) return;
    int e = edge_list[j];
    float d = dist[e];
    float inv = 1.f / d;
    float base = PI_ * d / RC_;
    float s1, c1;
    __sincosf(base, &s1, &c1);
    float twoc = c1 + c1;
    u16* rb = rbf_bf + (size_t)j * 32;
    float sprev = 0.f, scur = s1;
    #pragma unroll
    for (int k = 0; k < RBFN; k++) {
        rb[k] = f2b(scur * inv);
        float snext = twoc * scur - sprev;
        sprev = scur; scur = snext;
    }
    #pragma unroll
    for (int k = RBFN; k < 32; k++) rb[k] = 0;
    cut_p[j] = 0.5f * (c1 + 1.f) * (d < RC_ ? 1.f : 0.f);
    dst_p[j] = graph[2 * e + 1];
    sense_p[3 * j + 0] = sense[3 * e + 0];
    sense_p[3 * j + 1] = sense[3 * e + 1];
    sense_p[3 * j + 2] = sense[3 * e + 2];
}

// ---------------------------------------------------------------- fused node MLP (iter-0 message path)
// Ob = (silu(A@W1^T + b1)) @ W2^T + b2.  A:(M,K1) bf16, W1:(128,K1), W2:(384,128).
// PACK layout (for edge gather): row of 384 u16 per node:
//   [0..255]  = (comp0, comp1) interleaved at f*2 + c   (c = gn>>7 for gn<256)
//   [256..383]= comp2 planar at 256 + (gn&127)
template<int K1, bool PACK>
__global__ __launch_bounds__(256) void mlp_kernel(const u16* __restrict__ A,
    const u16* __restrict__ W1, const float* __restrict__ b1,
    const u16* __restrict__ W2, const float* __restrict__ b2,
    u16* __restrict__ Ob, int M)
{
    __shared__ u16 As[64][KB + LPAD];
    __shared__ u16 Ws[128][KB + LPAD];
    __shared__ u16 T[64][KB + LPAD];
    const int bm = blockIdx.x * 64;
    const int tid = threadIdx.x;
    const int wave = tid >> 6, lane = tid & 63;
    const int wm  = (wave >> 1) * 32;
    const int wn1 = (wave & 1) * 64;
    const int wn  = (wave & 1) * 32;
    const int quad = lane >> 4, lr = lane & 15;
    const int r = tid >> 2, q = tid & 3;

    floatx4 acc1[2][4];
    #pragma unroll
    for (int i = 0; i < 2; i++)
        #pragma unroll
        for (int j = 0; j < 4; j++) acc1[i][j] = (floatx4)0.f;

    for (int ko = 0; ko < K1; ko += KB) {
        {
            int gm = bm + r;
            u16* dA = &As[r][q * 32];
            if (gm < M) {
                const u16* ap = A + (size_t)gm * K1 + ko + q * 32;
                #pragma unroll
                for (int x = 0; x < 32; x += 8)
                    *(bf16x8*)&dA[x] = *(const bf16x8*)(ap + x);
            } else {
                #pragma unroll
                for (int x = 0; x < 32; x += 8)
                    *(bf16x8*)&dA[x] = (bf16x8)0;
            }
            #pragma unroll
            for (int h = 0; h < 2; h++) {
                int wr = r + h * 64;
                const u16* wp = W1 + (size_t)wr * K1 + ko + q * 32;
                u16* dW = &Ws[wr][q * 32];
                #pragma unroll
                for (int x = 0; x < 32; x += 8)
                    *(bf16x8*)&dW[x] = *(const bf16x8*)(wp + x);
            }
        }
        __syncthreads();
        #pragma unroll
        for (int kk = 0; kk < KB; kk += 32) {
            bf16x8 a0 = *(const bf16x8*)&As[wm + lr     ][kk + quad * 8];
            bf16x8 a1 = *(const bf16x8*)&As[wm + 16 + lr][kk + quad * 8];
            #pragma unroll
            for (int j = 0; j < 4; j++) {
                bf16x8 b = *(const bf16x8*)&Ws[wn1 + j * 16 + lr][kk + quad * 8];
                acc1[0][j] = __builtin_amdgcn_mfma_f32_16x16x32_bf16(a0, b, acc1[0][j], 0, 0, 0);
                acc1[1][j] = __builtin_amdgcn_mfma_f32_16x16x32_bf16(a1, b, acc1[1][j], 0, 0, 0);
            }
        }
        __syncthreads();
    }
    #pragma unroll
    for (int i = 0; i < 2; i++) {
        #pragma unroll
        for (int j = 0; j < 4; j++) {
            int col = wn1 + j * 16 + lr;
            float bb = b1[col];
            #pragma unroll
            for (int rr = 0; rr < 4; rr++) {
                int row = wm + i * 16 + quad * 4 + rr;
                float v = acc1[i][j][rr] + bb;
                v = v / (1.f + __expf(-v));
                T[row][col] = f2b(v);
            }
        }
    }
    __syncthreads();

    for (int c0 = 0; c0 < F3; c0 += 64) {
        {
            const u16* wp = W2 + (size_t)(c0 + r) * KB + q * 32;
            u16* dW = &Ws[r][q * 32];
            #pragma unroll
            for (int x = 0; x < 32; x += 8)
                *(bf16x8*)&dW[x] = *(const bf16x8*)(wp + x);
        }
        __syncthreads();
        floatx4 acc2[2][2];
        #pragma unroll
        for (int i = 0; i < 2; i++)
            #pragma unroll
            for (int j = 0; j < 2; j++) acc2[i][j] = (floatx4)0.f;
        #pragma unroll
        for (int kk = 0; kk < KB; kk += 32) {
            bf16x8 a0 = *(const bf16x8*)&T[wm + lr     ][kk + quad * 8];
            bf16x8 a1 = *(const bf16x8*)&T[wm + 16 + lr][kk + quad * 8];
            bf16x8 b0 = *(const bf16x8*)&Ws[wn + lr     ][kk + quad * 8];
            bf16x8 b1 = *(const bf16x8*)&Ws[wn + 16 + lr][kk + quad * 8];
            acc2[0][0] = __builtin_amdgcn_mfma_f32_16x16x32_bf16(a0, b0, acc2[0][0], 0, 0, 0);
            acc2[0][1] = __builtin_amdgcn_mfma_f32_16x16x32_bf16(a0, b1, acc2[0][1], 0, 0, 0);
            acc2[1][0] = __builtin_amdgcn_mfma_f32_16x16x32_bf16(a1, b0, acc2[1][0], 0, 0, 0);
            acc2[1][1] = __builtin_amdgcn_mfma_f32_16x16x32_bf16(a1, b1, acc2[1][1], 0, 0, 0);
        }
        #pragma unroll
        for (int i = 0; i < 2; i++) {
            #pragma unroll
            for (int j = 0; j < 2; j++) {
                int gn = c0 + wn + j * 16 + lr;
                float bb = b2[gn];
                #pragma unroll
                for (int rr = 0; rr < 4; rr++) {
                    int gm = bm + wm + i * 16 + quad * 4 + rr;
                    if (gm < M) {
                        u16 val = f2b(acc2[i][j][rr] + bb);
                        if (PACK) {
                            int off = (gn < 256) ? ((gn & 127) * 2 + (gn >> 7))
                                                 : (256 + (gn & 127));
                            Ob[(size_t)gm * F3 + off] = val;
                        } else {
                            Ob[(size_t)gm * F3 + gn] = val;
                        }
                    }
                }
            }
        }
        __syncthreads();
    }
}

// Dual GEMM: U = A@Wu^T, V = A@Wv^T (K=128, Nc=128). bf16 outs.
// A staged ONCE per block; bn (output-col half) folded into an in-block loop.
__global__ __launch_bounds__(256) void gemm_uv(const u16* __restrict__ A,
    const u16* __restrict__ Wu, const u16* __restrict__ Wv,
    u16* __restrict__ U, u16* __restrict__ V, int M)
{
    __shared__ u16 As[64][KB + LPAD];
    __shared__ u16 Bu[64][KB + LPAD];
    __shared__ u16 Bv[64][KB + LPAD];
    const int bm = blockIdx.x * 64;
    const int tid = threadIdx.x;
    const int r = tid >> 2;
    const int q = tid & 3;
    const int wave = tid >> 6;
    const int lane = tid & 63;
    const int wm = (wave >> 1) * 32;
    const int wn = (wave & 1) * 32;
    const int quad = lane >> 4;
    const int lr = lane & 15;

    {
        int gm = bm + r;
        u16* dA = &As[r][q * 32];
        if (gm < M) {
            const u16* ap = A + (size_t)gm * KB + q * 32;
            #pragma unroll
            for (int x = 0; x < 32; x += 8)
                *(bf16x8*)&dA[x] = *(const bf16x8*)(ap + x);
        } else {
            #pragma unroll
            for (int x = 0; x < 32; x += 8)
                *(bf16x8*)&dA[x] = (bf16x8)0;
        }
    }

    #pragma unroll
    for (int bn = 0; bn < FD; bn += 64) {
        {
            int gn = bn + r;
            const u16* up = Wu + (size_t)gn * KB + q * 32;
            const u16* vp = Wv + (size_t)gn * KB + q * 32;
            u16* dU = &Bu[r][q * 32];
            u16* dV = &Bv[r][q * 32];
            #pragma unroll
            for (int x = 0; x < 32; x += 8) {
                *(bf16x8*)&dU[x] = *(const bf16x8*)(up + x);
                *(bf16x8*)&dV[x] = *(const bf16x8*)(vp + x);
            }
        }
        __syncthreads();
        floatx4 au[2][2], av[2][2];
        #pragma unroll
        for (int i = 0; i < 2; i++)
            #pragma unroll
            for (int j = 0; j < 2; j++) { au[i][j] = (floatx4)0.f; av[i][j] = (floatx4)0.f; }
        #pragma unroll
        for (int kk = 0; kk < KB; kk += 32) {
            bf16x8 a0 = *(const bf16x8*)&As[wm + lr     ][kk + quad * 8];
            bf16x8 a1 = *(const bf16x8*)&As[wm + 16 + lr][kk + quad * 8];
            bf16x8 u0 = *(const bf16x8*)&Bu[wn + lr     ][kk + quad * 8];
            bf16x8 u1 = *(const bf16x8*)&Bu[wn + 16 + lr][kk + quad * 8];
            bf16x8 v0 = *(const bf16x8*)&Bv[wn + lr     ][kk + quad * 8];
            bf16x8 v1 = *(const bf16x8*)&Bv[wn + 16 + lr][kk + quad * 8];
            au[0][0] = __builtin_amdgcn_mfma_f32_16x16x32_bf16(a0, u0, au[0][0], 0, 0, 0);
            au[0][1] = __builtin_amdgcn_mfma_f32_16x16x32_bf16(a0, u1, au[0][1], 0, 0, 0);
            au[1][0] = __builtin_amdgcn_mfma_f32_16x16x32_bf16(a1, u0, au[1][0], 0, 0, 0);
            au[1][1] = __builtin_amdgcn_mfma_f32_16x16x32_bf16(a1, u1, au[1][1], 0, 0, 0);
            av[0][0] = __builtin_amdgcn_mfma_f32_16x16x32_bf16(a0, v0, av[0][0], 0, 0, 0);
            av[0][1] = __builtin_amdgcn_mfma_f32_16x16x32_bf16(a0, v1, av[0][1], 0, 0, 0);
            av[1][0] = __builtin_amdgcn_mfma_f32_16x16x32_bf16(a1, v0, av[1][0], 0, 0, 0);
            av[1][1] = __builtin_amdgcn_mfma_f32_16x16x32_bf16(a1, v1, av[1][1], 0, 0, 0);
        }
        #pragma unroll
        for (int i = 0; i < 2; i++) {
            #pragma unroll
            for (int j = 0; j < 2; j++) {
                int gn = bn + wn + j * 16 + lr;
                #pragma unroll
                for (int rr = 0; rr < 4; rr++) {
                    int gm = bm + wm + i * 16 + quad * 4 + rr;
                    if (gm < M) {
                        U[(size_t)gm * FD + gn] = f2b(au[i][j][rr]);
                        V[(size_t)gm * FD + gn] = f2b(av[i][j][rr]);
                    }
                }
            }
        }
        __syncthreads();   // Bu/Bv fully consumed before restage
    }
}

// ---------------------------------------------------------------- edge aggregate (MFMA dist_rep)
// 256 threads/node — PROVEN 138µs form, do not modify. Per 16-edge tile: dist_rep via 24
// MFMAs -> planar bf16 sdrep in LDS; gathers via packed (pair + planar) bf16 rows;
// serial runtime-bound nh loop (unroll / pair-gather / 512-thread variants all measured slower).
__global__ __launch_bounds__(256) void edge_mfma_kernel(
    const u16* __restrict__ rbf_bf, const float* __restrict__ cut_p,
    const float* __restrict__ sense_p, const int* __restrict__ dst_p,
    const u16* __restrict__ ewb, const float* __restrict__ eb,
    const u16* __restrict__ a_pk, const float* __restrict__ s_in,
    const float* __restrict__ v_in, const u16* __restrict__ v_pk,
    const int* __restrict__ row_ptr,
    float* __restrict__ s_out, u16* __restrict__ s_obf,
    float* __restrict__ v_out, u16* __restrict__ v_obf)
{
    __shared__ u16   sdrep[16 * SDS];   // planar bf16: [e][col] — 12.25 KB
    __shared__ float scut[16];
    __shared__ float ssen[16][4];
    __shared__ int   sdst[16];
    __shared__ float red[4 * 128];

    const int n = blockIdx.x;
    const int tid = threadIdx.x;
    const int wave = tid >> 6;
    const int lane = tid & 63;
    const int quad = lane >> 4;
    const int lr = lane & 15;
    const int f = tid & 127;
    const int half = tid >> 7;

    int beg = row_ptr[n], end = row_ptr[n + 1];
    float accs = 0.f, accv0 = 0.f, accv1 = 0.f, accv2 = 0.f;

    for (int t0 = beg; t0 < end; t0 += 16) {
        int cnt = end - t0; if (cnt > 16) cnt = 16;
        __syncthreads();   // previous tile fully consumed
        if (tid < 16) {
            scut[tid] = (tid < cnt) ? cut_p[t0 + tid] : 0.f;
            sdst[tid] = (tid < cnt) ? dst_p[t0 + tid] : 0;
        }
        if (tid >= 64 && tid < 64 + 3 * cnt) {
            int x = tid - 64;
            ssen[x / 3][x % 3] = sense_p[3 * t0 + x];
        }
        // MFMA: A = rbf rows (lane m=lr = edge), B = ew rows (6 col-tiles/wave)
        bf16x8 afrag;
        int ge = t0 + lr;
        if (ge < end) afrag = *(const bf16x8*)&rbf_bf[(size_t)ge * 32 + quad * 8];
        else          afrag = (bf16x8)0;
        floatx4 dacc[6];
        #pragma unroll
        for (int nt = 0; nt < 6; nt++) {
            int nrow = (wave * 6 + nt) * 16 + lr;
            bf16x8 bfrag = *(const bf16x8*)&ewb[(size_t)nrow * 32 + quad * 8];
            dacc[nt] = __builtin_amdgcn_mfma_f32_16x16x32_bf16(afrag, bfrag, (floatx4)0.f, 0, 0, 0);
        }
        __syncthreads();   // staged scalars visible
        // epilogue: (d + eb) * cut -> planar bf16 sdrep; C/D layout col=lr, row(edge)=quad*4+rr
        #pragma unroll
        for (int nt = 0; nt < 6; nt++) {
            int ncol = (wave * 6 + nt) * 16 + lr;
            float ebn = eb[ncol];
            #pragma unroll
            for (int rr = 0; rr < 4; rr++) {
                int e = quad * 4 + rr;
                sdrep[e * SDS + ncol] = f2b((dacc[nt][rr] + ebn) * scut[e]);
            }
        }
        __syncthreads();   // sdrep ready
        // aggregation: half h handles up to 8 edges
        int nh = cnt - half * 8; if (nh > 8) nh = 8;
        for (int k = 0; k < nh; k++) {
            int e = half * 8 + k;
            int dst = sdst[e];
            const u16* sr = &sdrep[e * SDS];
            float drv = b2f(sr[f]);
            float drs = b2f(sr[FD + f]);
            float drd = b2f(sr[2 * FD + f]);
            const u16* ar = a_pk + (size_t)dst * F3;
            u32 ap = *(const u32*)(ar + f * 2);
            float rv = b2f((u16)(ap & 0xffff)) * drv;
            float rs = b2f((u16)(ap >> 16))    * drs;
            float rd = b2f(ar[256 + f])        * drd;
            accs += rs;
            const u16* vr = v_pk + (size_t)dst * F3;
            u32 vp = *(const u32*)(vr + f * 2);
            accv0 += b2f((u16)(vp & 0xffff)) * rv + ssen[e][0] * rd;
            accv1 += b2f((u16)(vp >> 16))    * rv + ssen[e][1] * rd;
            accv2 += b2f(vr[256 + f])        * rv + ssen[e][2] * rd;
        }
    }
    // combine halves, write
    __syncthreads();
    if (half == 1) {
        red[f] = accs; red[128 + f] = accv0; red[256 + f] = accv1; red[384 + f] = accv2;
    }
    __syncthreads();
    if (half == 0) {
        accs  += red[f];       accv0 += red[128 + f];
        accv1 += red[256 + f]; accv2 += red[384 + f];
        int nb = n * FD + f;
        float so = s_in[nb] + 2.f * accs;
        s_out[nb] = so; s_obf[nb] = f2b(so);
        int vb = n * F3 + f;
        float w0 = v_in[vb]           + 2.f * accv0;
        float w1 = v_in[vb + FD]      + 2.f * accv1;
        float w2 = v_in[vb + 2 * FD]  + 2.f * accv2;
        v_out[vb]          = w0; v_obf[vb]          = f2b(w0);
        v_out[vb + FD]     = w1; v_obf[vb + FD]     = f2b(w1);
        v_out[vb + 2 * FD] = w2; v_obf[vb + 2 * FD] = f2b(w2);
    }
}

// ---------------------------------------------------------------- fused mlp2 + build_h + update + NEXT
// a2 = (silu(h@aw1^T+ab1))@aw2^T+ab2 with h = [s_mid, |Vv|] built in A-staging (no h_bf).
// GEMM2 chunks (avv,asv,ass per f-half) with SOFTWARE-PIPELINED weight staging: Ws halves
// alternate, piece p+1's loads issue before piece p's MFMAs, one barrier per piece.
// ass chunk performs the node update inline AND deposits fresh s (bf16) into As.  Then:
//   LAST=false: appended mlp1 of the NEXT iteration (A = As, out = a_pk, PACK).
//   LAST=true : appended final head (GEMM ow1 + silu + ow2-dot -> nodeval), f32 T aliased onto Ws.
template<bool LAST>
__global__ __launch_bounds__(256) void mlp2_update_next_kernel(
    const u16* __restrict__ sbf_mid, const float* __restrict__ s_mid,
    const float* __restrict__ v_mid,
    const u16* __restrict__ Uv, const u16* __restrict__ Vv,
    const u16* __restrict__ W1, const float* __restrict__ b1,
    const u16* __restrict__ W2, const float* __restrict__ b2,
    float* __restrict__ s_out,
    float* __restrict__ v_out, u16* __restrict__ v_pk,
    const u16* __restrict__ N_W1, const float* __restrict__ N_b1,
    const u16* __restrict__ N_W2, const float* __restrict__ N_b2,
    u16* __restrict__ a_pk,
    const u16* __restrict__ H_W1, const float* __restrict__ H_b1,
    const float* __restrict__ ow2, const float* __restrict__ ob2,
    float* __restrict__ nodeval, int M)
{
    __shared__ u16 As[64][KB + LPAD];
    __shared__ u16 Ws[128][KB + LPAD];
    __shared__ u16 T[64][KB + LPAD];
    const int bm = blockIdx.x * 64;
    const int tid = threadIdx.x;
    const int wave = tid >> 6, lane = tid & 63;
    const int wm  = (wave >> 1) * 32;
    const int wn1 = (wave & 1) * 64;
    const int wn  = (wave & 1) * 32;
    const int quad = lane >> 4, lr = lane & 15;
    const int r = tid >> 2, q = tid & 3;

    floatx4 acc1[2][4];
    #pragma unroll
    for (int i = 0; i < 2; i++)
        #pragma unroll
        for (int j = 0; j < 4; j++) acc1[i][j] = (floatx4)0.f;

    // ---- GEMM1, ko chunk 0: A cols = s_mid bf16
    {
        int gm = bm + r;
        u16* dA = &As[r][q * 32];
        if (gm < M) {
            const u16* ap = sbf_mid + (size_t)gm * FD + q * 32;
            #pragma unroll
            for (int x = 0; x < 32; x += 8)
                *(bf16x8*)&dA[x] = *(const bf16x8*)(ap + x);
        } else {
            #pragma unroll
            for (int x = 0; x < 32; x += 8)
                *(bf16x8*)&dA[x] = (bf16x8)0;
        }
        #pragma unroll
        for (int h = 0; h < 2; h++) {
            int wr = r + h * 64;
            const u16* wp = W1 + (size_t)wr * F2 + q * 32;
            u16* dW = &Ws[wr][q * 32];
            #pragma unroll
            for (int x = 0; x < 32; x += 8)
                *(bf16x8*)&dW[x] = *(const bf16x8*)(wp + x);
        }
    }
    __syncthreads();
    #pragma unroll
    for (int kk = 0; kk < KB; kk += 32) {
        bf16x8 a0 = *(const bf16x8*)&As[wm + lr     ][kk + quad * 8];
        bf16x8 a1 = *(const bf16x8*)&As[wm + 16 + lr][kk + quad * 8];
        #pragma unroll
        for (int j = 0; j < 4; j++) {
            bf16x8 b = *(const bf16x8*)&Ws[wn1 + j * 16 + lr][kk + quad * 8];
            acc1[0][j] = __builtin_amdgcn_mfma_f32_16x16x32_bf16(a0, b, acc1[0][j], 0, 0, 0);
            acc1[1][j] = __builtin_amdgcn_mfma_f32_16x16x32_bf16(a1, b, acc1[1][j], 0, 0, 0);
        }
    }
    __syncthreads();
    // ---- GEMM1, ko chunk 1: A cols = |Vv| computed inline (build_h fused)
    {
        int gm = bm + r;
        u16* dA = &As[r][q * 32];
        if (gm < M) {
            const u16* vvp = Vv + (size_t)gm * F3 + q * 32;
            bf16x8 c0[4], c1[4], c2[4];
            #pragma unroll
            for (int t = 0; t < 4; t++) {
                c0[t] = *(const bf16x8*)(vvp + t * 8);
                c1[t] = *(const bf16x8*)(vvp + FD + t * 8);
                c2[t] = *(const bf16x8*)(vvp + 2 * FD + t * 8);
            }
            #pragma unroll
            for (int t = 0; t < 4; t++) {
                #pragma unroll
                for (int x = 0; x < 8; x++) {
                    float a = b2f((u16)c0[t][x]);
                    float b = b2f((u16)c1[t][x]);
                    float c = b2f((u16)c2[t][x]);
                    dA[t * 8 + x] = f2b(sqrtf(a * a + b * b + c * c));
                }
            }
        } else {
            #pragma unroll
            for (int x = 0; x < 32; x += 8)
                *(bf16x8*)&dA[x] = (bf16x8)0;
        }
        #pragma unroll
        for (int h = 0; h < 2; h++) {
            int wr = r + h * 64;
            const u16* wp = W1 + (size_t)wr * F2 + KB + q * 32;
            u16* dW = &Ws[wr][q * 32];
            #pragma unroll
            for (int x = 0; x < 32; x += 8)
                *(bf16x8*)&dW[x] = *(const bf16x8*)(wp + x);
        }
    }
    __syncthreads();
    #pragma unroll
    for (int kk = 0; kk < KB; kk += 32) {
        bf16x8 a0 = *(const bf16x8*)&As[wm + lr     ][kk + quad * 8];
        bf16x8 a1 = *(const bf16x8*)&As[wm + 16 + lr][kk + quad * 8];
        #pragma unroll
        for (int j = 0; j < 4; j++) {
            bf16x8 b = *(const bf16x8*)&Ws[wn1 + j * 16 + lr][kk + quad * 8];
            acc1[0][j] = __builtin_amdgcn_mfma_f32_16x16x32_bf16(a0, b, acc1[0][j], 0, 0, 0);
            acc1[1][j] = __builtin_amdgcn_mfma_f32_16x16x32_bf16(a1, b, acc1[1][j], 0, 0, 0);
        }
    }
    __syncthreads();
    // T = silu(acc1 + b1) as bf16
    #pragma unroll
    for (int i = 0; i < 2; i++) {
        #pragma unroll
        for (int j = 0; j < 4; j++) {
            int col = wn1 + j * 16 + lr;
            float bb = b1[col];
            #pragma unroll
            for (int rr = 0; rr < 4; rr++) {
                int row = wm + i * 16 + quad * 4 + rr;
                float v = acc1[i][j][rr] + bb;
                v = v / (1.f + __expf(-v));
                T[row][col] = f2b(v);
            }
        }
    }

    // ---- GEMM2 (pipelined): pp order = part-major (avv,asv,ass per part).
    //      c0(pp) = (pp%3)*128 + (pp/3)*64.  Ws halves alternate per pp.
    float avvr[2][2][4], asvr[2][2][4];
    {
        // prologue: stage pp=0 (c0=0) into Ws half 0  (Ws last read before prior barrier)
        const u16* wp = W2 + (size_t)r * KB + q * 32;
        u16* dW = &Ws[r][q * 32];
        #pragma unroll
        for (int x = 0; x < 32; x += 8)
            *(bf16x8*)&dW[x] = *(const bf16x8*)(wp + x);
    }
    __syncthreads();   // covers T-write AND Ws half-0 stage
    #pragma unroll
    for (int pp = 0; pp < 6; pp++) {
        const int part  = pp / 3;
        const int piece = pp % 3;
        const int c0 = piece * 128 + part * 64;
        const int hcur = (pp & 1) * 64;
        if (pp < 5) {
            const int c0n = ((pp + 1) % 3) * 128 + ((pp + 1) / 3) * 64;
            const int hnext = ((pp + 1) & 1) * 64;
            const u16* wp = W2 + (size_t)(c0n + r) * KB + q * 32;
            u16* dW = &Ws[hnext + r][q * 32];
            #pragma unroll
            for (int x = 0; x < 32; x += 8)
                *(bf16x8*)&dW[x] = *(const bf16x8*)(wp + x);
        }
        floatx4 acc2[2][2];
        #pragma unroll
        for (int i = 0; i < 2; i++)
            #pragma unroll
            for (int j = 0; j < 2; j++) acc2[i][j] = (floatx4)0.f;
        #pragma unroll
        for (int kk = 0; kk < KB; kk += 32) {
            bf16x8 a0 = *(const bf16x8*)&T[wm + lr     ][kk + quad * 8];
            bf16x8 a1 = *(const bf16x8*)&T[wm + 16 + lr][kk + quad * 8];
            bf16x8 b0 = *(const bf16x8*)&Ws[hcur + wn + lr     ][kk + quad * 8];
            bf16x8 b1 = *(const bf16x8*)&Ws[hcur + wn + 16 + lr][kk + quad * 8];
            acc2[0][0] = __builtin_amdgcn_mfma_f32_16x16x32_bf16(a0, b0, acc2[0][0], 0, 0, 0);
            acc2[0][1] = __builtin_amdgcn_mfma_f32_16x16x32_bf16(a0, b1, acc2[0][1], 0, 0, 0);
            acc2[1][0] = __builtin_amdgcn_mfma_f32_16x16x32_bf16(a1, b0, acc2[1][0], 0, 0, 0);
            acc2[1][1] = __builtin_amdgcn_mfma_f32_16x16x32_bf16(a1, b1, acc2[1][1], 0, 0, 0);
        }
        if (piece == 0) {
            #pragma unroll
            for (int i = 0; i < 2; i++)
                #pragma unroll
                for (int j = 0; j < 2; j++) {
                    int gn = c0 + wn + j * 16 + lr;
                    float bb = b2[gn];
                    #pragma unroll
                    for (int rr = 0; rr < 4; rr++)
                        avvr[i][j][rr] = acc2[i][j][rr] + bb;
                }
        } else if (piece == 1) {
            #pragma unroll
            for (int i = 0; i < 2; i++)
                #pragma unroll
                for (int j = 0; j < 2; j++) {
                    int gn = c0 + wn + j * 16 + lr;
                    float bb = b2[gn];
                    #pragma unroll
                    for (int rr = 0; rr < 4; rr++)
                        asvr[i][j][rr] = acc2[i][j][rr] + bb;
                }
        } else {
            // ass chunk: full node update + As s-deposit
            #pragma unroll
            for (int i = 0; i < 2; i++) {
                #pragma unroll
                for (int j = 0; j < 2; j++) {
                    int gn = c0 + wn + j * 16 + lr;
                    int f  = gn - 256;          // = part*64 + wn + j*16 + lr
                    float bb = b2[gn];
                    #pragma unroll
                    for (int rr = 0; rr < 4; rr++) {
                        int row = wm + i * 16 + quad * 4 + rr;
                        int gm = bm + row;
                        if (gm < M) {
                            float ass = acc2[i][j][rr] + bb;
                            float asv = asvr[i][j][rr];
                            float avv = avvr[i][j][rr];
                            int vb = gm * F3 + f;
                            float u0 = b2f(Uv[vb]);
                            float u1 = b2f(Uv[vb + FD]);
                            float u2 = b2f(Uv[vb + 2 * FD]);
                            float w0 = b2f(Vv[vb]);
                            float w1 = b2f(Vv[vb + FD]);
                            float w2 = b2f(Vv[vb + 2 * FD]);
                            float dot = u0 * w0 + u1 * w1 + u2 * w2;
                            int nb = gm * FD + f;
                            float so = s_mid[nb] + ass + asv * dot;
                            s_out[nb] = so;
                            As[row][f] = f2b(so);
                            float y0 = v_mid[vb]          + avv * u0;
                            float y1 = v_mid[vb + FD]     + avv * u1;
                            float y2 = v_mid[vb + 2 * FD] + avv * u2;
                            v_out[vb]          = y0;
                            v_out[vb + FD]     = y1;
                            v_out[vb + 2 * FD] = y2;
                            char* vpb = (char*)v_pk + (size_t)gm * (2 * F3);
                            *(u32*)(vpb + 4 * f) = pack2(y0, y1);
                            *(u16*)(vpb + 512 + 2 * f) = f2b(y2);
                        } else {
                            As[row][f] = 0;
                        }
                    }
                }
            }
        }
        __syncthreads();
    }
    // As now holds this block's fresh s (bf16), all 64 rows x 128 cols.

    if constexpr (!LAST) {
        // ---------------- appended mlp1 of next iteration (A = As, K=128)
        {
            #pragma unroll
            for (int h = 0; h < 2; h++) {
                int wr = r + h * 64;
                const u16* wp = N_W1 + (size_t)wr * KB + q * 32;
                u16* dW = &Ws[wr][q * 32];
                #pragma unroll
                for (int x = 0; x < 32; x += 8)
                    *(bf16x8*)&dW[x] = *(const bf16x8*)(wp + x);
            }
        }
        __syncthreads();
        #pragma unroll
        for (int i = 0; i < 2; i++)
            #pragma unroll
            for (int j = 0; j < 4; j++) acc1[i][j] = (floatx4)0.f;
        #pragma unroll
        for (int kk = 0; kk < KB; kk += 32) {
            bf16x8 a0 = *(const bf16x8*)&As[wm + lr     ][kk + quad * 8];
            bf16x8 a1 = *(const bf16x8*)&As[wm + 16 + lr][kk + quad * 8];
            #pragma unroll
            for (int j = 0; j < 4; j++) {
                bf16x8 b = *(const bf16x8*)&Ws[wn1 + j * 16 + lr][kk + quad * 8];
                acc1[0][j] = __builtin_amdgcn_mfma_f32_16x16x32_bf16(a0, b, acc1[0][j], 0, 0, 0);
                acc1[1][j] = __builtin_amdgcn_mfma_f32_16x16x32_bf16(a1, b, acc1[1][j], 0, 0, 0);
            }
        }
        __syncthreads();
        #pragma unroll
        for (int i = 0; i < 2; i++) {
            #pragma unroll
            for (int j = 0; j < 4; j++) {
                int col = wn1 + j * 16 + lr;
                float bb = N_b1[col];
                #pragma unroll
                for (int rr = 0; rr < 4; rr++) {
                    int row = wm + i * 16 + quad * 4 + rr;
                    float v = acc1[i][j][rr] + bb;
                    v = v / (1.f + __expf(-v));
                    T[row][col] = f2b(v);
                }
            }
        }
        // GEMM2 (pipelined, 6 pieces of 64 cols, Ws halves alternate)
        {
            const u16* wp = N_W2 + (size_t)r * KB + q * 32;
            u16* dW = &Ws[r][q * 32];
            #pragma unroll
            for (int x = 0; x < 32; x += 8)
                *(bf16x8*)&dW[x] = *(const bf16x8*)(wp + x);
        }
        __syncthreads();   // covers T-write AND Ws half-0 stage
        #pragma unroll
        for (int pp = 0; pp < 6; pp++) {
            const int c0 = pp * 64;
            const int hcur = (pp & 1) * 64;
            if (pp < 5) {
                const int hnext = ((pp + 1) & 1) * 64;
                const u16* wp = N_W2 + (size_t)((pp + 1) * 64 + r) * KB + q * 32;
                u16* dW = &Ws[hnext + r][q * 32];
                #pragma unroll
                for (int x = 0; x < 32; x += 8)
                    *(bf16x8*)&dW[x] = *(const bf16x8*)(wp + x);
            }
            floatx4 acc2[2][2];
            #pragma unroll
            for (int i = 0; i < 2; i++)
                #pragma unroll
                for (int j = 0; j < 2; j++) acc2[i][j] = (floatx4)0.f;
            #pragma unroll
            for (int kk = 0; kk < KB; kk += 32) {
                bf16x8 a0 = *(const bf16x8*)&T[wm + lr     ][kk + quad * 8];
                bf16x8 a1 = *(const bf16x8*)&T[wm + 16 + lr][kk + quad * 8];
                bf16x8 b0 = *(const bf16x8*)&Ws[hcur + wn + lr     ][kk + quad * 8];
                bf16x8 b1 = *(const bf16x8*)&Ws[hcur + wn + 16 + lr][kk + quad * 8];
                acc2[0][0] = __builtin_amdgcn_mfma_f32_16x16x32_bf16(a0, b0, acc2[0][0], 0, 0, 0);
                acc2[0][1] = __builtin_amdgcn_mfma_f32_16x16x32_bf16(a0, b1, acc2[0][1], 0, 0, 0);
                acc2[1][0] = __builtin_amdgcn_mfma_f32_16x16x32_bf16(a1, b0, acc2[1][0], 0, 0, 0);
                acc2[1][1] = __builtin_amdgcn_mfma_f32_16x16x32_bf16(a1, b1, acc2[1][1], 0, 0, 0);
            }
            #pragma unroll
            for (int i = 0; i < 2; i++) {
                #pragma unroll
                for (int j = 0; j < 2; j++) {
                    int gn = c0 + wn + j * 16 + lr;
                    float bb = N_b2[gn];
                    #pragma unroll
                    for (int rr = 0; rr < 4; rr++) {
                        int gm = bm + wm + i * 16 + quad * 4 + rr;
                        if (gm < M) {
                            u16 val = f2b(acc2[i][j][rr] + bb);
                            int off = (gn < 256) ? ((gn & 127) * 2 + (gn >> 7))
                                                 : (256 + (gn & 127));
                            a_pk[(size_t)gm * F3 + off] = val;
                        }
                    }
                }
            }
            __syncthreads();
        }
    } else {
        // ---------------- appended final head: t = silu(s@ow1^T+ob1); nodeval = t·ow2 + ob2
        {
            #pragma unroll
            for (int h = 0; h < 2; h++) {
                int wr = r + h * 64;
                const u16* wp = H_W1 + (size_t)wr * KB + q * 32;
                u16* dW = &Ws[wr][q * 32];
                #pragma unroll
                for (int x = 0; x < 32; x += 8)
                    *(bf16x8*)&dW[x] = *(const bf16x8*)(wp + x);
            }
        }
        __syncthreads();
        #pragma unroll
        for (int i = 0; i < 2; i++)
            #pragma unroll
            for (int j = 0; j < 4; j++) acc1[i][j] = (floatx4)0.f;
        #pragma unroll
        for (int kk = 0; kk < KB; kk += 32) {
            bf16x8 a0 = *(const bf16x8*)&As[wm + lr     ][kk + quad * 8];
            bf16x8 a1 = *(const bf16x8*)&As[wm + 16 + lr][kk + quad * 8];
            #pragma unroll
            for (int j = 0; j < 4; j++) {
                bf16x8 b = *(const bf16x8*)&Ws[wn1 + j * 16 + lr][kk + quad * 8];
                acc1[0][j] = __builtin_amdgcn_mfma_f32_16x16x32_bf16(a0, b, acc1[0][j], 0, 0, 0);
                acc1[1][j] = __builtin_amdgcn_mfma_f32_16x16x32_bf16(a1, b, acc1[1][j], 0, 0, 0);
            }
        }
        __syncthreads();   // Ws fully consumed; As fully consumed
        float* Tf   = (float*)&Ws[0][0];   // 64 x 132 f32 = 33792 B <= 34816 B
        float* ow2s = (float*)&As[0][0];   // 128 f32 = 512 B
        if (tid < KB) ow2s[tid] = ow2[tid];
        #pragma unroll
        for (int i = 0; i < 2; i++) {
            #pragma unroll
            for (int j = 0; j < 4; j++) {
                int col = wn1 + j * 16 + lr;
                float bb = H_b1[col];
                #pragma unroll
                for (int rr = 0; rr < 4; rr++) {
                    int row = wm + i * 16 + quad * 4 + rr;
                    float v = acc1[i][j][rr] + bb;
                    v = v / (1.f + __expf(-v));
                    Tf[row * 132 + col] = v;
                }
            }
        }
        __syncthreads();
        int nl = tid >> 2, seg = tid & 3;
        float v = 0.f;
        #pragma unroll
        for (int x = 0; x < 32; x++) {
            int col = seg * 32 + x;
            v += Tf[nl * 132 + col] * ow2s[col];
        }
        v += __shfl_down(v, 2);
        v += __shfl_down(v, 1);
        if (seg == 0) {
            int gm = bm + nl;
            if (gm < M) nodeval[gm] = v + ob2[0];
        }
    }
}

__global__ __launch_bounds__(1024) void mol_reduce_kernel(const float* __restrict__ nodeval,
    const int* __restrict__ gidx, float* __restrict__ out)
{
    __shared__ float mol[NMOL];
    int tid = threadIdx.x;
    if (tid < NMOL) mol[tid] = 0.f;
    __syncthreads();
    int cur = -1; float acc = 0.f;
    for (int x = tid; x < NN; x += 1024) {
        int g = gidx[x];
        float v = nodeval[x];
        if (g != cur) {
            if (cur >= 0) atomicAdd(&mol[cur], acc);
            cur = g; acc = v;
        } else acc += v;
    }
    if (cur >= 0) atomicAdd(&mol[cur], acc);
    __syncthreads();
    if (tid < NMOL) out[tid] = mol[tid];
}

// ---------------------------------------------------------------- launch
extern "C" void kernel_launch(void* const* d_in, const int* in_sizes, int n_in,
                              void* d_out, int out_size, void* d_ws, size_t ws_size,
                              hipStream_t stream)
{
    const int*   z     = (const int*)d_in[0];
    const int*   graph = (const int*)d_in[1];
    const float* dist  = (const float*)d_in[2];
    const float* sense = (const float*)d_in[3];
    const int*   gidx  = (const int*)d_in[4];
    const float* emb   = (const float*)d_in[5];
    const float* mw1   = (const float*)d_in[6];
    const float* mb1   = (const float*)d_in[7];
    const float* mw2   = (const float*)d_in[8];
    const float* mb2   = (const float*)d_in[9];
    const float* ew    = (const float*)d_in[10];
    const float* eb    = (const float*)d_in[11];
    const float* uw    = (const float*)d_in[12];
    const float* vw    = (const float*)d_in[13];
    const float* aw1   = (const float*)d_in[14];
    const float* ab1   = (const float*)d_in[15];
    const float* aw2   = (const float*)d_in[16];
    const float* ab2   = (const float*)d_in[17];
    const float* ow1   = (const float*)d_in[18];
    const float* ob1   = (const float*)d_in[19];
    const float* ow2   = (const float*)d_in[20];
    const float* ob2   = (const float*)d_in[21];
    float* out = (float*)d_out;

    // ---- workspace carve-up ----
    float* W = (float*)d_ws;
    float* s_a    = W; W += (size_t)NN * FD;
    float* s_b    = W; W += (size_t)NN * FD;
    float* v_a    = W; W += (size_t)NN * F3;
    float* v_b    = W; W += (size_t)NN * F3;
    float* cut_p  = W; W += (size_t)NE;
    float* sns_p  = W; W += (size_t)NE * 3;
    float* nodeval= W; W += (size_t)NN;
    u16* U = (u16*)W;
    u16* sbf_a = U; U += (size_t)NN * FD;
    u16* sbf_b = U; U += (size_t)NN * FD;
    u16* vbf_b = U; U += (size_t)NN * F3;
    u16* a_pk  = U; U += (size_t)NN * F3;
    u16* v_pk  = U; U += (size_t)NN * F3;
    u16* h_bf  = U; U += (size_t)NN * F2;   // unused (kept for layout stability)
    u16* a2_bf = U; U += (size_t)NN * F3;   // unused (kept for layout stability)
    u16* Uv_bf = U; U += (size_t)NN * F3;
    u16* Vv_bf = U; U += (size_t)NN * F3;
    u16* rbf_bf= U; U += (size_t)NE * 32;
    u16* ewb   = U; U += (size_t)NITER * F3 * 32;
    u16* wb    = U; U += 557056;
    int* ip = (int*)U;
    int* row_ptr   = ip; ip += NN + 1;
    int* cnt       = ip; ip += NN;
    int* cursor    = ip; ip += NN;
    int* edge_list = ip; ip += NE;
    int* dst_p     = ip; ip += NE;

    // bf16 weight table offsets
    u16* wb_mw1 = wb;            // 3*128*128
    u16* wb_mw2 = wb + 49152;    // 3*384*128
    u16* wb_uw  = wb + 196608;   // 3*128*128
    u16* wb_vw  = wb + 245760;   // 3*128*128
    u16* wb_aw1 = wb + 294912;   // 3*128*256
    u16* wb_aw2 = wb + 393216;   // 3*384*128
    u16* wb_ow1 = wb + 540672;   // 128*128

    const int TB = 256;
    dim3 b256(TB);

    // --- precompute (fused init covers: weight cvt, ew cvt, embed, v/v_pk/cnt zero) ---
    init_all_kernel<<<dim3((NN * F3 + TB - 1) / TB), b256, 0, stream>>>(
        mw1, 49152, mw2, 147456, uw, 49152, vw, 49152, aw1, 98304, aw2, 147456,
        ow1, 16384, wb, ew, ewb, z, emb, s_a, sbf_a, v_a, (int*)v_pk, cnt);
    csr_count_kernel<<<dim3((NE + TB - 1) / TB), b256, 0, stream>>>(graph, cnt);
    csr_scan_kernel<<<dim3(1), dim3(1024), 0, stream>>>(cnt, row_ptr, cursor);
    csr_scatter_kernel<<<dim3((NE + TB - 1) / TB), b256, 0, stream>>>(graph, cursor, edge_list);
    edge_stream_kernel<<<dim3((NE + TB - 1) / TB), b256, 0, stream>>>(
        edge_list, graph, dist, sense, rbf_bf, cut_p, sns_p, dst_p);

    dim3 gM((NN + 63) / 64);                   // fused MLPs / head
    dim3 gUV((3 * NN + 63) / 64);              // M=3N, bn folded in-block

    // iter-0 message MLP (later iterations' mlp1 are fused into mlp2_update_next)
    mlp_kernel<128, true><<<gM, b256, 0, stream>>>(sbf_a,
        wb_mw1, mb1, wb_mw2, mb2, a_pk, NN);

    for (int i = 0; i < NITER; i++) {
        edge_mfma_kernel<<<dim3(NN), b256, 0, stream>>>(
            rbf_bf, cut_p, sns_p, dst_p,
            ewb + (size_t)i * F3 * 32, eb + (size_t)i * F3,
            a_pk, s_a, v_a, v_pk, row_ptr, s_b, sbf_b, v_b, vbf_b);
        gemm_uv<<<gUV, b256, 0, stream>>>(vbf_b, wb_uw + (size_t)i * FD * FD,
            wb_vw + (size_t)i * FD * FD, Uv_bf, Vv_bf, 3 * NN);
        if (i < NITER - 1) {
            mlp2_update_next_kernel<false><<<gM, b256, 0, stream>>>(
                sbf_b, s_b, v_b, Uv_bf, Vv_bf,
                wb_aw1 + (size_t)i * FD * F2, ab1 + (size_t)i * FD,
                wb_aw2 + (size_t)i * F3 * FD, ab2 + (size_t)i * F3,
                s_a, v_a, v_pk,
                wb_mw1 + (size_t)(i + 1) * FD * FD, mb1 + (size_t)(i + 1) * FD,
                wb_mw2 + (size_t)(i + 1) * F3 * FD, mb2 + (size_t)(i + 1) * F3, a_pk,
                nullptr, nullptr, nullptr, nullptr, nullptr, NN);
        } else {
            mlp2_update_next_kernel<true><<<gM, b256, 0, stream>>>(
                sbf_b, s_b, v_b, Uv_bf, Vv_bf,
                wb_aw1 + (size_t)i * FD * F2, ab1 + (size_t)i * FD,
                wb_aw2 + (size_t)i * F3 * FD, ab2 + (size_t)i * F3,
                s_a, v_a, v_pk,
                nullptr, nullptr, nullptr, nullptr, nullptr,
                wb_ow1, ob1, ow2, ob2, nodeval, NN);
        }
    }

    mol_reduce_kernel<<<dim3(1), dim3(1024), 0, stream>>>(nodeval, gidx, out);
}